// Round 4
// baseline (957.416 us; speedup 1.0000x reference)
//
#include <hip/hip_runtime.h>
#include <cstddef>

#define S_LEN 16384
#define DIM   400
#define HID   256
#define NTAG  12
#define TSTART 10
#define TSTOP  11
#define FNEG  -10000.0f

// chunked scan: 512 output chunks of 32 steps, 16 warmup steps.
// 1024 blocks = 4 blocks/CU: the scan is per-wave latency-bound (u~0.38),
// so 4 independent waves/SIMD lift SIMD fill from 62% -> ~85%.
#define CHUNK_L 32
#define NCHUNK  512
#define WARM    16

typedef unsigned int   u32;
typedef unsigned short u16;
typedef _Float16 half2_t __attribute__((ext_vector_type(2)));
typedef short    short8 __attribute__((ext_vector_type(8)));
typedef float    f32x4  __attribute__((ext_vector_type(4)));
typedef unsigned short u16x4 __attribute__((ext_vector_type(4)));

__device__ __forceinline__ int sdot8f(u32 a, u32 b, int acc) {
#if defined(__has_builtin) && __has_builtin(__builtin_amdgcn_sdot8)
  return __builtin_amdgcn_sdot8((int)a, (int)b, acc, false);
#else
  #pragma unroll
  for (int i = 0; i < 8; ++i) {
    int ai = ((int)(a << (28 - 4 * i))) >> 28;
    int bi = ((int)(b << (28 - 4 * i))) >> 28;
    acc += ai * bi;
  }
  return acc;
#endif
}

__device__ __forceinline__ float sigmoidf_(float x) {
  return 1.0f / (1.0f + __expf(-x));
}
__device__ __forceinline__ float tanhf_(float x) {
  float e = __expf(2.0f * x);
  return 1.0f - 2.0f / (e + 1.0f);
}
__device__ __forceinline__ u16 f2bf(float f) {   // f32 -> bf16 RNE
  u32 u = __builtin_bit_cast(u32, f);
  u = u + 0x7FFFu + ((u >> 16) & 1u);
  return (u16)(u >> 16);
}

// ---------------------------------------------------------------------------
// Simple f32 -> bf16 convert (for x)
// ---------------------------------------------------------------------------
__global__ __launch_bounds__(256) void cvt_one(
    const float* __restrict__ in, u16* __restrict__ out, int n4)
{
  int i = blockIdx.x * 256 + threadIdx.x;
  if (i >= n4) return;
  float4 v = *(const float4*)(in + (size_t)i * 4);
  u16x4 o;
  o.x = f2bf(v.x); o.y = f2bf(v.y); o.z = f2bf(v.z); o.w = f2bf(v.w);
  *(u16x4*)(out + (size_t)i * 4) = o;
}

// ---------------------------------------------------------------------------
// Batched f32 -> bf16 weight convert.  blockIdx.y selects slice.
// ---------------------------------------------------------------------------
#define NCVT 8
__global__ __launch_bounds__(256) void cvt_multi(
    const float* __restrict__ s0, const float* __restrict__ s1,
    const float* __restrict__ s2, const float* __restrict__ s3,
    const float* __restrict__ s4, const float* __restrict__ s5,
    const float* __restrict__ s6, const float* __restrict__ s7,
    u16* __restrict__ d0, u16* __restrict__ d1,
    u16* __restrict__ d2, u16* __restrict__ d3,
    u16* __restrict__ d4, u16* __restrict__ d5,
    u16* __restrict__ d6, u16* __restrict__ d7,
    int n40, int n41, int n42, int n43, int n44, int n45, int n46, int n47)
{
  const int z = blockIdx.y;
  const float* src = (z==0)?s0:(z==1)?s1:(z==2)?s2:(z==3)?s3:(z==4)?s4:(z==5)?s5:(z==6)?s6:s7;
  u16* dst = (z==0)?d0:(z==1)?d1:(z==2)?d2:(z==3)?d3:(z==4)?d4:(z==5)?d5:(z==6)?d6:d7;
  const int n4 = (z==0)?n40:(z==1)?n41:(z==2)?n42:(z==3)?n43:(z==4)?n44:(z==5)?n45:(z==6)?n46:n47;
  int i = blockIdx.x * 256 + threadIdx.x;
  if (i >= n4) return;
  float4 v = *(const float4*)(src + (size_t)i * 4);
  u16x4 o;
  o.x = f2bf(v.x); o.y = f2bf(v.y); o.z = f2bf(v.z); o.w = f2bf(v.w);
  *(u16x4*)(dst + (size_t)i * 4) = o;
}

// ---------------------------------------------------------------------------
// Quantize Whh rows (4 mats x 1024 rows x 256) and h0 (4 rows x 256) to INT4
// with per-row scale.  One wave per row.
// ---------------------------------------------------------------------------
__global__ __launch_bounds__(256) void quant_whh4(
    const float* __restrict__ W0f, const float* __restrict__ W0b,
    const float* __restrict__ W1f, const float* __restrict__ W1b,
    const float* __restrict__ h0,
    u32* __restrict__ Wq4, float* __restrict__ Wsc,
    u32* __restrict__ h0q4, float* __restrict__ h0s)
{
  const int wave = threadIdx.x >> 6;
  const int lane = threadIdx.x & 63;
  const int row  = blockIdx.x * 4 + wave;
  if (row >= 4100) return;
  const float* src;
  if (row < 4096) {
    int mat = row >> 10, r = row & 1023;
    const float* W = (mat == 0) ? W0f : (mat == 1) ? W0b : (mat == 2) ? W1f : W1b;
    src = W + (size_t)r * HID;
  } else {
    src = h0 + (size_t)(row - 4096) * HID;
  }
  float4 v = *(const float4*)(src + lane * 4);
  float m = fmaxf(fmaxf(fabsf(v.x), fabsf(v.y)), fmaxf(fabsf(v.z), fabsf(v.w)));
#pragma unroll
  for (int off = 32; off; off >>= 1) m = fmaxf(m, __shfl_xor(m, off, 64));
  float inv   = (m > 0.f) ? 7.f / m : 0.f;
  float scale = (m > 0.f) ? m / 7.f : 0.f;
  int q0 = (int)rintf(v.x * inv);
  int q1 = (int)rintf(v.y * inv);
  int q2 = (int)rintf(v.z * inv);
  int q3 = (int)rintf(v.w * inv);
  u32 nib16 = (u32)(q0 & 15) | ((u32)(q1 & 15) << 4)
            | ((u32)(q2 & 15) << 8) | ((u32)(q3 & 15) << 12);
  u32 other = (u32)__shfl_xor((int)nib16, 1, 64);
  if ((lane & 1) == 0) {
    u32 word = nib16 | (other << 16);
    if (row < 4096) Wq4[(size_t)row * 32 + (lane >> 1)] = word;
    else            h0q4[(size_t)(row - 4096) * 32 + (lane >> 1)] = word;
  }
  if (lane == 0) {
    if (row < 4096) Wsc[row] = scale;
    else            h0s[row - 4096] = scale;
  }
}

// ---------------------------------------------------------------------------
// Fused highway layer (MFMA): computes G/N/L = A.W{g,n,l}^T + b in one pass
// (3 accumulators sharing the A tile), applies the highway combine in the
// epilogue, writes bf16.  Block tile 128(M) x 64(N); 4 waves 2x2, per-wave
// 64x32.  K-step 32, register-pipelined staging.  A bf16 [M,400]; W bf16
// [400,400] row-major (3 mats); out bf16 [M,400].
// ---------------------------------------------------------------------------
__global__ __launch_bounds__(256) void hw_fused(
    const u16* __restrict__ A,
    const u16* __restrict__ Wgb, const u16* __restrict__ Wnb,
    const u16* __restrict__ Wlb,
    const float* __restrict__ bg, const float* __restrict__ bnn,
    const float* __restrict__ bl,
    u16* __restrict__ outb)
{
  __shared__ u16 As[128 * 40];            // 10.0 KB
  __shared__ u16 Bs[3 * 64 * 40];         // 15.0 KB
  const int tid  = threadIdx.x;
  const int bm0  = blockIdx.x * 128;
  const int bn0  = blockIdx.y * 64;
  const int w    = tid >> 6;
  const int lane = tid & 63;
  const int quad = lane >> 4;
  const int l16  = lane & 15;
  const int wm0  = (w >> 1) * 64;
  const int wn0  = (w & 1) * 32;
  const int K = DIM, N = DIM;

  f32x4 acc[3][4][2];
#pragma unroll
  for (int z = 0; z < 3; ++z)
#pragma unroll
    for (int i = 0; i < 4; ++i)
#pragma unroll
      for (int j = 0; j < 2; ++j) acc[z][i][j] = (f32x4){0.f, 0.f, 0.f, 0.f};

  short8 va[2], vb[3];
  // ---- preload k0 = 0 ----
#pragma unroll
  for (int i = 0; i < 2; ++i) {
    int c = tid + i * 256, row = c >> 2, koff = (c & 3) * 8, gk = koff;
    va[i] = (short8){0,0,0,0,0,0,0,0};
    if (gk + 8 <= K)
      va[i] = *(const short8*)(A + (size_t)(bm0 + row) * K + gk);
  }
#pragma unroll
  for (int i = 0; i < 3; ++i) {
    int c = tid + i * 256, z = c >> 8, r = (c >> 2) & 63, koff = (c & 3) * 8;
    int gn = bn0 + r, gk = koff;
    const u16* W = (z == 0) ? Wgb : (z == 1) ? Wnb : Wlb;
    vb[i] = (short8){0,0,0,0,0,0,0,0};
    if (gn < N && gk + 8 <= K)
      vb[i] = *(const short8*)(W + (size_t)gn * K + gk);
  }

  for (int k0 = 0; k0 < K; k0 += 32) {
    __syncthreads();
#pragma unroll
    for (int i = 0; i < 2; ++i) {
      int c = tid + i * 256, row = c >> 2, koff = (c & 3) * 8;
      *(short8*)(&As[row * 40 + koff]) = va[i];
    }
#pragma unroll
    for (int i = 0; i < 3; ++i) {
      int c = tid + i * 256, z = c >> 8, r = (c >> 2) & 63, koff = (c & 3) * 8;
      *(short8*)(&Bs[z * 2560 + r * 40 + koff]) = vb[i];
    }
    __syncthreads();

    // ---- preload next tile while MFMAs run ----
    int kn = k0 + 32;
    if (kn < K) {
#pragma unroll
      for (int i = 0; i < 2; ++i) {
        int c = tid + i * 256, row = c >> 2, koff = (c & 3) * 8, gk = kn + koff;
        va[i] = (short8){0,0,0,0,0,0,0,0};
        if (gk + 8 <= K)
          va[i] = *(const short8*)(A + (size_t)(bm0 + row) * K + gk);
        else if (gk < K)
          for (int j = 0; j < K - gk; ++j) va[i][j] = (short)A[(size_t)(bm0 + row) * K + gk + j];
      }
#pragma unroll
      for (int i = 0; i < 3; ++i) {
        int c = tid + i * 256, z = c >> 8, r = (c >> 2) & 63, koff = (c & 3) * 8;
        int gn = bn0 + r, gk = kn + koff;
        const u16* W = (z == 0) ? Wgb : (z == 1) ? Wnb : Wlb;
        vb[i] = (short8){0,0,0,0,0,0,0,0};
        if (gn < N) {
          if (gk + 8 <= K)
            vb[i] = *(const short8*)(W + (size_t)gn * K + gk);
          else if (gk < K)
            for (int j = 0; j < K - gk; ++j) vb[i][j] = (short)W[(size_t)gn * K + gk + j];
        }
      }
    }

    short8 af[4];
#pragma unroll
    for (int mi = 0; mi < 4; ++mi)
      af[mi] = *(const short8*)(&As[(wm0 + mi * 16 + l16) * 40 + quad * 8]);
#pragma unroll
    for (int z = 0; z < 3; ++z) {
      short8 bf0 = *(const short8*)(&Bs[z * 2560 + (wn0 + l16) * 40 + quad * 8]);
      short8 bf1 = *(const short8*)(&Bs[z * 2560 + (wn0 + 16 + l16) * 40 + quad * 8]);
#pragma unroll
      for (int mi = 0; mi < 4; ++mi) {
        acc[z][mi][0] = __builtin_amdgcn_mfma_f32_16x16x32_bf16(af[mi], bf0, acc[z][mi][0], 0, 0, 0);
        acc[z][mi][1] = __builtin_amdgcn_mfma_f32_16x16x32_bf16(af[mi], bf1, acc[z][mi][1], 0, 0, 0);
      }
    }
  }

  // ---- epilogue: highway combine -> bf16 ----
#pragma unroll
  for (int ni = 0; ni < 2; ++ni) {
    int n = bn0 + wn0 + ni * 16 + l16;
    if (n >= N) continue;
    float bgv = bg[n], bnv = bnn[n], blv = bl[n];
#pragma unroll
    for (int mi = 0; mi < 4; ++mi) {
#pragma unroll
      for (int r = 0; r < 4; ++r) {
        int m = bm0 + wm0 + mi * 16 + quad * 4 + r;
        float gv = acc[0][mi][ni][r] + bgv;
        float nv = acc[1][mi][ni][r] + bnv;
        float lv = acc[2][mi][ni][r] + blv;
        float g = sigmoidf_(gv);
        float v = g * fmaxf(nv, 0.f) + (1.f - g) * lv;
        outb[(size_t)m * N + n] = f2bf(v);
      }
    }
  }
}

// ---------------------------------------------------------------------------
// bf16 MFMA GEMM, z-batched, register-pipelined.  C = A.B^T + bias.
// A bf16 [M,K]; B bf16 [N,K]; z selects {B, bias, outF}.
// pack4: f16 gate-packed output oH + z*S_LEN*1024 (N==1024).
// Tile 128x128, 4 waves 2x2 (64x64), K-step 32, LDS stride 40.
// ---------------------------------------------------------------------------
__global__ __launch_bounds__(256) void gemm_multi(
    const u16* __restrict__ Ab,
    const u16* __restrict__ B0, const u16* __restrict__ B1,
    const float* __restrict__ bias0, const float* __restrict__ bias1,
    float* __restrict__ oF0, float* __restrict__ oF1,
    u16* __restrict__ oH, int pack4,
    int M, int N, int K)
{
  __shared__ u16 As[128 * 40];
  __shared__ u16 Bs[128 * 40];
  const int z = blockIdx.z;
  const u16* B      = (z == 0) ? B0 : B1;
  const float* bias = (z == 0) ? bias0 : bias1;
  float* outF       = (z == 0) ? oF0 : oF1;
  u16* outH         = pack4 ? (oH + (size_t)z * S_LEN * 1024) : nullptr;

  const int tid  = threadIdx.x;
  const int bm0  = blockIdx.x * 128;
  const int bn0  = blockIdx.y * 128;
  const int w    = tid >> 6;
  const int lane = tid & 63;
  const int quad = lane >> 4;
  const int l16  = lane & 15;
  const int wm0  = (w >> 1) * 64;
  const int wn0  = (w & 1) * 64;

  f32x4 acc[4][4];
#pragma unroll
  for (int i = 0; i < 4; ++i)
#pragma unroll
    for (int j = 0; j < 4; ++j) acc[i][j] = (f32x4){0.f, 0.f, 0.f, 0.f};

  short8 va[2], vb[2];
  // ---- preload k0 = 0 ----
#pragma unroll
  for (int i = 0; i < 2; ++i) {
    int c = tid + i * 256, row = c >> 2, koff = (c & 3) * 8, gk = koff;
    va[i] = (short8){0,0,0,0,0,0,0,0};
    vb[i] = (short8){0,0,0,0,0,0,0,0};
    if (gk + 8 <= K) {
      va[i] = *(const short8*)(Ab + (size_t)(bm0 + row) * K + gk);
      if (bn0 + row < N)
        vb[i] = *(const short8*)(B + (size_t)(bn0 + row) * K + gk);
    }
  }

  for (int k0 = 0; k0 < K; k0 += 32) {
    __syncthreads();
#pragma unroll
    for (int i = 0; i < 2; ++i) {
      int c = tid + i * 256, row = c >> 2, koff = (c & 3) * 8;
      *(short8*)(&As[row * 40 + koff]) = va[i];
      *(short8*)(&Bs[row * 40 + koff]) = vb[i];
    }
    __syncthreads();

    // ---- preload next tile ----
    int kn = k0 + 32;
    if (kn < K) {
#pragma unroll
      for (int i = 0; i < 2; ++i) {
        int c = tid + i * 256, row = c >> 2, koff = (c & 3) * 8, gk = kn + koff;
        va[i] = (short8){0,0,0,0,0,0,0,0};
        vb[i] = (short8){0,0,0,0,0,0,0,0};
        if (gk + 8 <= K) {
          va[i] = *(const short8*)(Ab + (size_t)(bm0 + row) * K + gk);
          if (bn0 + row < N)
            vb[i] = *(const short8*)(B + (size_t)(bn0 + row) * K + gk);
        } else if (gk < K) {
          for (int j = 0; j < K - gk; ++j) {
            va[i][j] = (short)Ab[(size_t)(bm0 + row) * K + gk + j];
            if (bn0 + row < N) vb[i][j] = (short)B[(size_t)(bn0 + row) * K + gk + j];
          }
        }
      }
    }

    short8 af[4], bf[4];
#pragma unroll
    for (int mi = 0; mi < 4; ++mi)
      af[mi] = *(const short8*)(&As[(wm0 + mi * 16 + l16) * 40 + quad * 8]);
#pragma unroll
    for (int ni = 0; ni < 4; ++ni)
      bf[ni] = *(const short8*)(&Bs[(wn0 + ni * 16 + l16) * 40 + quad * 8]);
#pragma unroll
    for (int mi = 0; mi < 4; ++mi)
#pragma unroll
      for (int ni = 0; ni < 4; ++ni)
        acc[mi][ni] = __builtin_amdgcn_mfma_f32_16x16x32_bf16(
            af[mi], bf[ni], acc[mi][ni], 0, 0, 0);
  }

#pragma unroll
  for (int mi = 0; mi < 4; ++mi) {
#pragma unroll
    for (int ni = 0; ni < 4; ++ni) {
      int n = bn0 + wn0 + ni * 16 + l16;
      if (n >= N) continue;
      float bv = bias ? bias[n] : 0.f;
#pragma unroll
      for (int r = 0; r < 4; ++r) {
        int m = bm0 + wm0 + mi * 16 + quad * 4 + r;
        float v = acc[mi][ni][r] + bv;
        if (pack4) {
          outH[((size_t)m * 256 + (n & 255)) * 4 + (n >> 8)] =
              __builtin_bit_cast(u16, (_Float16)v);
        } else {
          outF[(size_t)m * N + n] = v;
        }
      }
    }
  }
}

// ---------------------------------------------------------------------------
// Chunked LSTM scan (cell-owned int4 dot8).  256 threads, thread j owns cell
// j (all 4 gates, 128 weight words; compiler may AGPR-allocate -- VALU reads
// AGPRs directly on gfx950, proven non-critical by rounds 1-3).
// Changes vs the 116us baseline:
//  * 4 blocks/CU (CHUNK_L=32, 1024 blocks): the scan is per-wave latency-
//    bound (per-wave issue occupancy ~0.38 measured); 4 independent
//    waves/SIMD lift fill to ~85%.
//  * h repack via ds_or (atomicOr into next buffer) + 3-buffer rotation,
//    replacing 3 serial __shfl_xor LDS-pipe hops on the recurrence critical
//    path.  Bit layout of packed h is unchanged (nibble j&7 of word j>>3).
//  * One barrier per step, as before.
// ---------------------------------------------------------------------------
__global__ __launch_bounds__(256, 4) void lstm_scan(
    const u32* __restrict__ Wq4,    // [2 dirs][1024][32] packed int4 words
    const float* __restrict__ WscL, // [2 dirs][1024]
    const u32* __restrict__ h0q4,   // [4][32]
    const float* __restrict__ h0s,  // [4]
    const float* __restrict__ c0,   // [4][256]
    int row_base,
    const u16* __restrict__ P,      // [2][S][256][4] f16 gate-packed
    u16* __restrict__ Xout)         // [S][512] bf16
{
  const int k    = blockIdx.x;         // chunk
  const int dir  = blockIdx.y;
  const int j    = threadIdx.x;        // cell 0..255
  const int lane = j & 63;

  __shared__ u32 hq[3][32];            // rotating int4 h buffers

  const int out_lo = k * CHUNK_L;
  const int out_hi = out_lo + CHUNK_L - 1;
  int tstart, nsteps;
  bool real_init;
  if (dir == 0) {
    int wlo = out_lo - WARM; if (wlo < 0) wlo = 0;
    tstart = wlo;
    nsteps = out_hi - wlo + 1;
    real_init = (wlo == 0);
  } else {
    int whi = out_hi + WARM; if (whi > S_LEN - 1) whi = S_LEN - 1;
    tstart = whi;
    nsteps = whi - out_lo + 1;
    real_init = (whi == S_LEN - 1);
  }
  const int swrite = nsteps - CHUNK_L;

  u32 wi[32], wf[32], wg[32], wo[32];
  {
    const u32* base = Wq4 + (size_t)dir * 1024 * 32;
    const uint4* pi = (const uint4*)(base + (size_t)(j      ) * 32);
    const uint4* pf = (const uint4*)(base + (size_t)(j + 256) * 32);
    const uint4* pg = (const uint4*)(base + (size_t)(j + 512) * 32);
    const uint4* po = (const uint4*)(base + (size_t)(j + 768) * 32);
#pragma unroll
    for (int q = 0; q < 8; ++q) {
      uint4 a = pi[q], b = pf[q], c = pg[q], d = po[q];
      wi[4*q] = a.x; wi[4*q+1] = a.y; wi[4*q+2] = a.z; wi[4*q+3] = a.w;
      wf[4*q] = b.x; wf[4*q+1] = b.y; wf[4*q+2] = b.z; wf[4*q+3] = b.w;
      wg[4*q] = c.x; wg[4*q+1] = c.y; wg[4*q+2] = c.z; wg[4*q+3] = c.w;
      wo[4*q] = d.x; wo[4*q+1] = d.y; wo[4*q+2] = d.z; wo[4*q+3] = d.w;
    }
  }
  const float sci = WscL[dir * 1024 + j];
  const float scf = WscL[dir * 1024 + j + 256];
  const float scg = WscL[dir * 1024 + j + 512];
  const float sco = WscL[dir * 1024 + j + 768];

  float c_state = real_init ? c0[(row_base + dir) * HID + j] : 0.f;
  if (j < 32) {
    hq[0][j] = real_init ? h0q4[(size_t)(row_base + dir) * 32 + j] : 0u;
    hq[1][j] = 0u;                       // first OR target
  }
  float hscale = real_init ? h0s[row_base + dir] : (1.f / 7.f);
  __syncthreads();

  const ptrdiff_t pstep = dir ? -1024 : 1024;
  const ptrdiff_t xstep = dir ? -512 : 512;
  const u16* pp = P + (size_t)dir * S_LEN * 1024 + (size_t)tstart * 1024 + j * 4;
  u16* xp = Xout + (size_t)tstart * 512 + dir * HID + j;

  uint2 p0 = *(const uint2*)pp;
  uint2 p1 = (nsteps > 1) ? *(const uint2*)(pp + pstep) : p0;
  const u16* pf2 = pp + 2 * pstep;

  int cur = 0, nxt = 1, zer = 2;
  for (int s = 0; s < nsteps; ++s) {
    uint2 p2 = (s < nsteps - 2) ? *(const uint2*)pf2 : p1;
    pf2 += pstep;

    // zero the buffer that will be OR-target next step (off critical path)
    if (j < 32) hq[zer][j] = 0u;

    u32 hword = hq[cur][lane & 31];
    int ai = 0, af = 0, ag = 0, ao = 0;
#pragma unroll
    for (int q = 0; q < 32; ++q) {
      u32 hs = (u32)__builtin_amdgcn_readlane((int)hword, q);
      ai = sdot8f(wi[q], hs, ai);
      af = sdot8f(wf[q], hs, af);
      ag = sdot8f(wg[q], hs, ag);
      ao = sdot8f(wo[q], hs, ao);
    }
    half2_t pif = __builtin_bit_cast(half2_t, p0.x);
    half2_t pgo = __builtin_bit_cast(half2_t, p0.y);
    float gi = sigmoidf_((float)ai * (sci * hscale) + (float)pif[0]);
    float gf = sigmoidf_((float)af * (scf * hscale) + (float)pif[1]);
    float gg = tanhf_   ((float)ag * (scg * hscale) + (float)pgo[0]);
    float go = sigmoidf_((float)ao * (sco * hscale) + (float)pgo[1]);
    c_state = gf * c_state + gi * gg;
    float hv = go * tanhf_(c_state);

    int q4 = (int)rintf(hv * 7.f);
    u32 v = ((u32)(q4 & 15)) << (4 * (j & 7));
    atomicOr(&hq[nxt][j >> 3], v);       // ds_or_b32, fire-and-forget
    if (s >= swrite) *xp = f2bf(hv);

    hscale = 1.f / 7.f;
    p0 = p1; p1 = p2;
    xp += xstep;
    __syncthreads();                     // ORs + zeroing complete
    int t = cur; cur = nxt; nxt = zer; zer = t;
  }
}

// ---------------------------------------------------------------------------
// CRF: parallel log-semiring chunk products + fold.
// ---------------------------------------------------------------------------
__global__ __launch_bounds__(192) void crf_chunk(
    const float* __restrict__ feats, const float* __restrict__ trans,
    float* __restrict__ Mc)
{
  __shared__ float tr[144];
  __shared__ float fb[128][12];
  __shared__ float accA[156];
  __shared__ float accB[156];
  const int tid = threadIdx.x;
  const int cb  = blockIdx.x;
  if (tid < 144) tr[tid] = trans[tid];
  for (int i = tid; i < 128 * 12; i += 192)
    fb[i / 12][i % 12] = feats[(size_t)cb * 128 * 12 + i];
  __syncthreads();

  const int ii = tid / 12, jj = tid % 12;
  const bool act = tid < 144;
  float* cur = accA;
  float* nxt = accB;
  if (act) cur[ii * 13 + jj] = tr[ii * 12 + jj] + fb[0][ii];
  __syncthreads();

  for (int t = 1; t < 128; ++t) {
    if (act) {
      float v[12];
      float m = FNEG * 4.f;
#pragma unroll
      for (int kk = 0; kk < 12; ++kk) {
        v[kk] = tr[ii * 12 + kk] + cur[kk * 13 + jj];
        m = fmaxf(m, v[kk]);
      }
      float ssum = 0.f;
#pragma unroll
      for (int kk = 0; kk < 12; ++kk) ssum += __expf(v[kk] - m);
      nxt[ii * 13 + jj] = fb[t][ii] + m + __logf(ssum);
    }
    __syncthreads();
    float* tmp = cur; cur = nxt; nxt = tmp;
  }
  if (act) Mc[(size_t)cb * 144 + ii * 12 + jj] = cur[ii * 13 + jj];
}

__global__ __launch_bounds__(64) void crf_fold(
    const float* __restrict__ Mc, const float* __restrict__ trans,
    float* __restrict__ outp)
{
  __shared__ float fv[12];
  __shared__ float nf[12];
  const int tid = threadIdx.x;
  if (tid < 12) fv[tid] = (tid == TSTART) ? 0.f : FNEG;
  __syncthreads();
  for (int cidx = 0; cidx < 128; ++cidx) {
    if (tid < 12) {
      const float* M = Mc + (size_t)cidx * 144 + tid * 12;
      float v[12];
      float m = FNEG * 4.f;
#pragma unroll
      for (int j = 0; j < 12; ++j) {
        v[j] = M[j] + fv[j];
        m = fmaxf(m, v[j]);
      }
      float s = 0.f;
#pragma unroll
      for (int j = 0; j < 12; ++j) s += __expf(v[j] - m);
      nf[tid] = m + __logf(s);
    }
    __syncthreads();
    if (tid < 12) fv[tid] = nf[tid];
    __syncthreads();
  }
  if (tid == 0) {
    float v[12];
    float m = FNEG * 4.f;
#pragma unroll
    for (int i = 0; i < 12; ++i) {
      v[i] = fv[i] + trans[TSTOP * 12 + i];
      m = fmaxf(m, v[i]);
    }
    float s = 0.f;
#pragma unroll
    for (int i = 0; i < 12; ++i) s += __expf(v[i] - m);
    outp[0] = m + __logf(s);
  }
}

// ---------------------------------------------------------------------------
extern "C" void kernel_launch(void* const* d_in, const int* in_sizes, int n_in,
                              void* d_out, int out_size, void* d_ws, size_t ws_size,
                              hipStream_t stream)
{
  (void)in_sizes; (void)n_in; (void)out_size; (void)ws_size;
  const float* x     = (const float*)d_in[0];
  const float* Wg    = (const float*)d_in[1];
  const float* bg    = (const float*)d_in[2];
  const float* Wn    = (const float*)d_in[3];
  const float* bnn   = (const float*)d_in[4];
  const float* Wl    = (const float*)d_in[5];
  const float* bl    = (const float*)d_in[6];
  const float* Wih0f = (const float*)d_in[7];
  const float* Whh0f = (const float*)d_in[8];
  const float* b0f   = (const float*)d_in[9];
  const float* Wih0b = (const float*)d_in[10];
  const float* Whh0b = (const float*)d_in[11];
  const float* b0b   = (const float*)d_in[12];
  const float* Wih1f = (const float*)d_in[13];
  const float* Whh1f = (const float*)d_in[14];
  const float* b1f   = (const float*)d_in[15];
  const float* Wih1b = (const float*)d_in[16];
  const float* Whh1b = (const float*)d_in[17];
  const float* b1b   = (const float*)d_in[18];
  const float* Wtag  = (const float*)d_in[19];
  const float* btag  = (const float*)d_in[20];
  const float* trans = (const float*)d_in[21];
  const float* h0    = (const float*)d_in[22];
  const float* c0    = (const float*)d_in[23];

  char* ws = (char*)d_ws;
  size_t off = 0;
  auto alloc = [&](size_t bytes) -> void* {
    void* p = ws + off;
    off += (bytes + 255) & ~(size_t)255;
    return p;
  };
  // Pbuf (64 MiB) | X1b (16 MiB bf16)
  u16* Pbuf = (u16*)alloc((size_t)2 * S_LEN * 1024 * 2);
  u16* X1b  = (u16*)alloc((size_t)S_LEN * 512 * 2);

  u16* xb      = (u16*)alloc((size_t)S_LEN * DIM * 2);
  u16* xhw1b   = (u16*)alloc((size_t)S_LEN * DIM * 2);
  u16* xhw2b   = (u16*)alloc((size_t)S_LEN * DIM * 2);
  u16* Wgb     = (u16*)alloc((size_t)2 * DIM * DIM * 2);
  u16* Wnb     = (u16*)alloc((size_t)2 * DIM * DIM * 2);
  u16* Wlb     = (u16*)alloc((size_t)2 * DIM * DIM * 2);
  u16* W0fb    = (u16*)alloc((size_t)1024 * DIM * 2);
  u16* W0bb    = (u16*)alloc((size_t)1024 * DIM * 2);
  u16* W1fb    = (u16*)alloc((size_t)1024 * 512 * 2);
  u16* W1bb    = (u16*)alloc((size_t)1024 * 512 * 2);
  u16* Wtagb   = (u16*)alloc((size_t)NTAG * 512 * 2);
  u32*   Wq4   = (u32*)alloc((size_t)4 * 1024 * 32 * 4);
  float* Wsc   = (float*)alloc((size_t)4096 * 4);
  u32*   h0q4b = (u32*)alloc((size_t)4 * 32 * 4);
  float* h0sb  = (float*)alloc((size_t)4 * 4);
  float* feats = (float*)alloc((size_t)S_LEN * NTAG * 4);
  float* Mc    = (float*)alloc((size_t)128 * 144 * 4);

  // 1) prep: int4 recurrent quant, x + weights -> bf16
  quant_whh4<<<1025, 256, 0, stream>>>(Whh0f, Whh0b, Whh1f, Whh1b, h0,
                                       Wq4, Wsc, h0q4b, h0sb);
  {
    int nx4 = S_LEN * DIM / 4;                       // 1,638,400
    cvt_one<<<(nx4 + 255) / 256, 256, 0, stream>>>(x, xb, nx4);
    int nHW = 2 * DIM * DIM / 4;
    int nP0 = 1024 * DIM / 4;
    int nP1 = 1024 * 512 / 4;
    int nTG = NTAG * 512 / 4;
    dim3 gC((131072 + 255) / 256, NCVT);
    cvt_multi<<<gC, 256, 0, stream>>>(Wg, Wn, Wl, Wih0f, Wih0b, Wih1f, Wih1b, Wtag,
                                      Wgb, Wnb, Wlb, W0fb, W0bb, W1fb, W1bb, Wtagb,
                                      nHW, nHW, nHW, nP0, nP0, nP1, nP1, nTG);
  }

  // 2) highway x2 (fused 3-GEMM + combine)
  dim3 gHW(S_LEN / 128, (DIM + 63) / 64);           // 128 x 7
  hw_fused<<<gHW, 256, 0, stream>>>(xb, Wgb, Wnb, Wlb, bg, bnn, bl, xhw1b);
  hw_fused<<<gHW, 256, 0, stream>>>(xhw1b, Wgb + 160000, Wnb + 160000,
                                    Wlb + 160000, bg + 400, bnn + 400, bl + 400,
                                    xhw2b);

  // 3) layer-0 input projections (z=2, f16 gate-packed)
  dim3 gP(S_LEN / 128, 1024 / 128, 2);
  gemm_multi<<<gP, 256, 0, stream>>>(xhw2b, W0fb, W0bb, b0f, b0b,
                                     nullptr, nullptr, Pbuf, 1,
                                     S_LEN, 1024, DIM);

  // 4) layer-0 bidirectional chunked scan -> X1b [S,512] bf16
  dim3 gS(NCHUNK, 2);
  lstm_scan<<<gS, 256, 0, stream>>>(Wq4, Wsc, h0q4b, h0sb, c0, 0, Pbuf, X1b);

  // 5) layer-1 input projections
  gemm_multi<<<gP, 256, 0, stream>>>(X1b, W1fb, W1bb, b1f, b1b,
                                     nullptr, nullptr, Pbuf, 1,
                                     S_LEN, 1024, 512);

  // 6) layer-1 chunked scan -> X1b reused as lstm_out (bf16)
  lstm_scan<<<gS, 256, 0, stream>>>(Wq4 + (size_t)2 * 1024 * 32, Wsc + 2048,
                                    h0q4b, h0sb, c0, 2, Pbuf, X1b);

  // 7) tag projection -> feats [S,12]
  dim3 gT(S_LEN / 128, 1, 1);
  gemm_multi<<<gT, 256, 0, stream>>>(X1b, Wtagb, nullptr, btag, nullptr,
                                     feats, nullptr, nullptr, 0,
                                     S_LEN, NTAG, 512);

  // 8) CRF log-partition
  crf_chunk<<<128, 192, 0, stream>>>(feats, trans, Mc);
  crf_fold<<<1, 64, 0, stream>>>(Mc, trans, (float*)d_out);
}

// Round 6
// 676.449 us; speedup vs baseline: 1.4154x; 1.4154x over previous
//
#include <hip/hip_runtime.h>
#include <cstddef>

#define S_LEN 16384
#define DIM   400
#define HID   256
#define NTAG  12
#define TSTART 10
#define TSTOP  11
#define FNEG  -10000.0f

// chunked scan: 256 output chunks of 64 steps, 16 warmup steps
#define CHUNK_L 64
#define NCHUNK  256
#define WARM    16

typedef unsigned int   u32;
typedef unsigned short u16;
typedef short    short8 __attribute__((ext_vector_type(8)));
typedef float    f32x4  __attribute__((ext_vector_type(4)));
typedef unsigned short u16x4 __attribute__((ext_vector_type(4)));

__device__ __forceinline__ int sdot8f(u32 a, u32 b, int acc) {
#if defined(__has_builtin) && __has_builtin(__builtin_amdgcn_sdot8)
  return __builtin_amdgcn_sdot8((int)a, (int)b, acc, false);
#else
  #pragma unroll
  for (int i = 0; i < 8; ++i) {
    int ai = ((int)(a << (28 - 4 * i))) >> 28;
    int bi = ((int)(b << (28 - 4 * i))) >> 28;
    acc += ai * bi;
  }
  return acc;
#endif
}

__device__ __forceinline__ float sigmoidf_(float x) {
  return 1.0f / (1.0f + __expf(-x));
}
__device__ __forceinline__ float tanhf_(float x) {
  float e = __expf(2.0f * x);
  return 1.0f - 2.0f / (e + 1.0f);
}
__device__ __forceinline__ u16 f2bf(float f) {   // f32 -> bf16 RNE
  u32 u = __builtin_bit_cast(u32, f);
  u = u + 0x7FFFu + ((u >> 16) & 1u);
  return (u16)(u >> 16);
}
__device__ __forceinline__ float h2f(u16 h) {
  return (float)__builtin_bit_cast(_Float16, h);
}

// ---------------------------------------------------------------------------
// Simple f32 -> bf16 convert (for x)
// ---------------------------------------------------------------------------
__global__ __launch_bounds__(256) void cvt_one(
    const float* __restrict__ in, u16* __restrict__ out, int n4)
{
  int i = blockIdx.x * 256 + threadIdx.x;
  if (i >= n4) return;
  float4 v = *(const float4*)(in + (size_t)i * 4);
  u16x4 o;
  o.x = f2bf(v.x); o.y = f2bf(v.y); o.z = f2bf(v.z); o.w = f2bf(v.w);
  *(u16x4*)(out + (size_t)i * 4) = o;
}

// ---------------------------------------------------------------------------
// Batched f32 -> bf16 weight convert.  blockIdx.y selects slice.
// ---------------------------------------------------------------------------
#define NCVT 8
__global__ __launch_bounds__(256) void cvt_multi(
    const float* __restrict__ s0, const float* __restrict__ s1,
    const float* __restrict__ s2, const float* __restrict__ s3,
    const float* __restrict__ s4, const float* __restrict__ s5,
    const float* __restrict__ s6, const float* __restrict__ s7,
    u16* __restrict__ d0, u16* __restrict__ d1,
    u16* __restrict__ d2, u16* __restrict__ d3,
    u16* __restrict__ d4, u16* __restrict__ d5,
    u16* __restrict__ d6, u16* __restrict__ d7,
    int n40, int n41, int n42, int n43, int n44, int n45, int n46, int n47)
{
  const int z = blockIdx.y;
  const float* src = (z==0)?s0:(z==1)?s1:(z==2)?s2:(z==3)?s3:(z==4)?s4:(z==5)?s5:(z==6)?s6:s7;
  u16* dst = (z==0)?d0:(z==1)?d1:(z==2)?d2:(z==3)?d3:(z==4)?d4:(z==5)?d5:(z==6)?d6:d7;
  const int n4 = (z==0)?n40:(z==1)?n41:(z==2)?n42:(z==3)?n43:(z==4)?n44:(z==5)?n45:(z==6)?n46:n47;
  int i = blockIdx.x * 256 + threadIdx.x;
  if (i >= n4) return;
  float4 v = *(const float4*)(src + (size_t)i * 4);
  u16x4 o;
  o.x = f2bf(v.x); o.y = f2bf(v.y); o.z = f2bf(v.z); o.w = f2bf(v.w);
  *(u16x4*)(dst + (size_t)i * 4) = o;
}

// ---------------------------------------------------------------------------
// Quantize Whh rows (4 mats x 1024 rows x 256) and h0 (4 rows x 256) to INT4
// with per-row scale.  One wave per row.
// ---------------------------------------------------------------------------
__global__ __launch_bounds__(256) void quant_whh4(
    const float* __restrict__ W0f, const float* __restrict__ W0b,
    const float* __restrict__ W1f, const float* __restrict__ W1b,
    const float* __restrict__ h0,
    u32* __restrict__ Wq4, float* __restrict__ Wsc,
    u32* __restrict__ h0q4, float* __restrict__ h0s)
{
  const int wave = threadIdx.x >> 6;
  const int lane = threadIdx.x & 63;
  const int row  = blockIdx.x * 4 + wave;
  if (row >= 4100) return;
  const float* src;
  if (row < 4096) {
    int mat = row >> 10, r = row & 1023;
    const float* W = (mat == 0) ? W0f : (mat == 1) ? W0b : (mat == 2) ? W1f : W1b;
    src = W + (size_t)r * HID;
  } else {
    src = h0 + (size_t)(row - 4096) * HID;
  }
  float4 v = *(const float4*)(src + lane * 4);
  float m = fmaxf(fmaxf(fabsf(v.x), fabsf(v.y)), fmaxf(fabsf(v.z), fabsf(v.w)));
#pragma unroll
  for (int off = 32; off; off >>= 1) m = fmaxf(m, __shfl_xor(m, off, 64));
  float inv   = (m > 0.f) ? 7.f / m : 0.f;
  float scale = (m > 0.f) ? m / 7.f : 0.f;
  int q0 = (int)rintf(v.x * inv);
  int q1 = (int)rintf(v.y * inv);
  int q2 = (int)rintf(v.z * inv);
  int q3 = (int)rintf(v.w * inv);
  u32 nib16 = (u32)(q0 & 15) | ((u32)(q1 & 15) << 4)
            | ((u32)(q2 & 15) << 8) | ((u32)(q3 & 15) << 12);
  u32 other = (u32)__shfl_xor((int)nib16, 1, 64);
  if ((lane & 1) == 0) {
    u32 word = nib16 | (other << 16);
    if (row < 4096) Wq4[(size_t)row * 32 + (lane >> 1)] = word;
    else            h0q4[(size_t)(row - 4096) * 32 + (lane >> 1)] = word;
  }
  if (lane == 0) {
    if (row < 4096) Wsc[row] = scale;
    else            h0s[row - 4096] = scale;
  }
}

// ---------------------------------------------------------------------------
// Fused highway layer (MFMA): computes G/N/L = A.W{g,n,l}^T + b in one pass
// (3 accumulators sharing the A tile), applies the highway combine in the
// epilogue, writes bf16.  Block tile 128(M) x 64(N); 4 waves 2x2, per-wave
// 64x32.  K-step 32, register-pipelined staging.  A bf16 [M,400]; W bf16
// [400,400] row-major (3 mats); out bf16 [M,400].
// ---------------------------------------------------------------------------
__global__ __launch_bounds__(256) void hw_fused(
    const u16* __restrict__ A,
    const u16* __restrict__ Wgb, const u16* __restrict__ Wnb,
    const u16* __restrict__ Wlb,
    const float* __restrict__ bg, const float* __restrict__ bnn,
    const float* __restrict__ bl,
    u16* __restrict__ outb)
{
  __shared__ u16 As[128 * 40];            // 10.0 KB
  __shared__ u16 Bs[3 * 64 * 40];         // 15.0 KB
  const int tid  = threadIdx.x;
  const int bm0  = blockIdx.x * 128;
  const int bn0  = blockIdx.y * 64;
  const int w    = tid >> 6;
  const int lane = tid & 63;
  const int quad = lane >> 4;
  const int l16  = lane & 15;
  const int wm0  = (w >> 1) * 64;
  const int wn0  = (w & 1) * 32;
  const int K = DIM, N = DIM;

  f32x4 acc[3][4][2];
#pragma unroll
  for (int z = 0; z < 3; ++z)
#pragma unroll
    for (int i = 0; i < 4; ++i)
#pragma unroll
      for (int j = 0; j < 2; ++j) acc[z][i][j] = (f32x4){0.f, 0.f, 0.f, 0.f};

  short8 va[2], vb[3];
  // ---- preload k0 = 0 ----
#pragma unroll
  for (int i = 0; i < 2; ++i) {
    int c = tid + i * 256, row = c >> 2, koff = (c & 3) * 8, gk = koff;
    va[i] = (short8){0,0,0,0,0,0,0,0};
    if (gk + 8 <= K)
      va[i] = *(const short8*)(A + (size_t)(bm0 + row) * K + gk);
  }
#pragma unroll
  for (int i = 0; i < 3; ++i) {
    int c = tid + i * 256, z = c >> 8, r = (c >> 2) & 63, koff = (c & 3) * 8;
    int gn = bn0 + r, gk = koff;
    const u16* W = (z == 0) ? Wgb : (z == 1) ? Wnb : Wlb;
    vb[i] = (short8){0,0,0,0,0,0,0,0};
    if (gn < N && gk + 8 <= K)
      vb[i] = *(const short8*)(W + (size_t)gn * K + gk);
  }

  for (int k0 = 0; k0 < K; k0 += 32) {
    __syncthreads();
#pragma unroll
    for (int i = 0; i < 2; ++i) {
      int c = tid + i * 256, row = c >> 2, koff = (c & 3) * 8;
      *(short8*)(&As[row * 40 + koff]) = va[i];
    }
#pragma unroll
    for (int i = 0; i < 3; ++i) {
      int c = tid + i * 256, z = c >> 8, r = (c >> 2) & 63, koff = (c & 3) * 8;
      *(short8*)(&Bs[z * 2560 + r * 40 + koff]) = vb[i];
    }
    __syncthreads();

    // ---- preload next tile while MFMAs run ----
    int kn = k0 + 32;
    if (kn < K) {
#pragma unroll
      for (int i = 0; i < 2; ++i) {
        int c = tid + i * 256, row = c >> 2, koff = (c & 3) * 8, gk = kn + koff;
        va[i] = (short8){0,0,0,0,0,0,0,0};
        if (gk + 8 <= K)
          va[i] = *(const short8*)(A + (size_t)(bm0 + row) * K + gk);
        else if (gk < K)
          for (int j = 0; j < K - gk; ++j) va[i][j] = (short)A[(size_t)(bm0 + row) * K + gk + j];
      }
#pragma unroll
      for (int i = 0; i < 3; ++i) {
        int c = tid + i * 256, z = c >> 8, r = (c >> 2) & 63, koff = (c & 3) * 8;
        int gn = bn0 + r, gk = kn + koff;
        const u16* W = (z == 0) ? Wgb : (z == 1) ? Wnb : Wlb;
        vb[i] = (short8){0,0,0,0,0,0,0,0};
        if (gn < N) {
          if (gk + 8 <= K)
            vb[i] = *(const short8*)(W + (size_t)gn * K + gk);
          else if (gk < K)
            for (int j = 0; j < K - gk; ++j) vb[i][j] = (short)W[(size_t)gn * K + gk + j];
        }
      }
    }

    short8 af[4];
#pragma unroll
    for (int mi = 0; mi < 4; ++mi)
      af[mi] = *(const short8*)(&As[(wm0 + mi * 16 + l16) * 40 + quad * 8]);
#pragma unroll
    for (int z = 0; z < 3; ++z) {
      short8 bf0 = *(const short8*)(&Bs[z * 2560 + (wn0 + l16) * 40 + quad * 8]);
      short8 bf1 = *(const short8*)(&Bs[z * 2560 + (wn0 + 16 + l16) * 40 + quad * 8]);
#pragma unroll
      for (int mi = 0; mi < 4; ++mi) {
        acc[z][mi][0] = __builtin_amdgcn_mfma_f32_16x16x32_bf16(af[mi], bf0, acc[z][mi][0], 0, 0, 0);
        acc[z][mi][1] = __builtin_amdgcn_mfma_f32_16x16x32_bf16(af[mi], bf1, acc[z][mi][1], 0, 0, 0);
      }
    }
  }

  // ---- epilogue: highway combine -> bf16 ----
#pragma unroll
  for (int ni = 0; ni < 2; ++ni) {
    int n = bn0 + wn0 + ni * 16 + l16;
    if (n >= N) continue;
    float bgv = bg[n], bnv = bnn[n], blv = bl[n];
#pragma unroll
    for (int mi = 0; mi < 4; ++mi) {
#pragma unroll
      for (int r = 0; r < 4; ++r) {
        int m = bm0 + wm0 + mi * 16 + quad * 4 + r;
        float gv = acc[0][mi][ni][r] + bgv;
        float nv = acc[1][mi][ni][r] + bnv;
        float lv = acc[2][mi][ni][r] + blv;
        float g = sigmoidf_(gv);
        float v = g * fmaxf(nv, 0.f) + (1.f - g) * lv;
        outb[(size_t)m * N + n] = f2bf(v);
      }
    }
  }
}

// ---------------------------------------------------------------------------
// bf16 MFMA GEMM, z-batched, register-pipelined.  C = A.B^T + bias.
// A bf16 [M,K]; B bf16 [N,K]; z selects {B, bias, outF}.
// pack4 (N==1024): f16 output in GATE-PLANAR layout
//   oH[((z*4 + (n>>8)) * S_LEN + m) * 256 + (n&255)]
// so a wave's 16 l16-consecutive cells are 32 B contiguous per quad-row
// (full 32B L2 sectors, no RMW) -- the old [cell][4] interleave wrote 2 B
// at stride 8 B (25% sector fill, ~4x write amplification on the 64 MiB P).
// Tile 128x128, 4 waves 2x2 (64x64), K-step 32, LDS stride 40.
// ---------------------------------------------------------------------------
__global__ __launch_bounds__(256) void gemm_multi(
    const u16* __restrict__ Ab,
    const u16* __restrict__ B0, const u16* __restrict__ B1,
    const float* __restrict__ bias0, const float* __restrict__ bias1,
    float* __restrict__ oF0, float* __restrict__ oF1,
    u16* __restrict__ oH, int pack4,
    int M, int N, int K)
{
  __shared__ u16 As[128 * 40];
  __shared__ u16 Bs[128 * 40];
  const int z = blockIdx.z;
  const u16* B      = (z == 0) ? B0 : B1;
  const float* bias = (z == 0) ? bias0 : bias1;
  float* outF       = (z == 0) ? oF0 : oF1;
  u16* outH         = pack4 ? (oH + (size_t)z * S_LEN * 1024) : nullptr;

  const int tid  = threadIdx.x;
  const int bm0  = blockIdx.x * 128;
  const int bn0  = blockIdx.y * 128;
  const int w    = tid >> 6;
  const int lane = tid & 63;
  const int quad = lane >> 4;
  const int l16  = lane & 15;
  const int wm0  = (w >> 1) * 64;
  const int wn0  = (w & 1) * 64;

  f32x4 acc[4][4];
#pragma unroll
  for (int i = 0; i < 4; ++i)
#pragma unroll
    for (int j = 0; j < 4; ++j) acc[i][j] = (f32x4){0.f, 0.f, 0.f, 0.f};

  short8 va[2], vb[2];
  // ---- preload k0 = 0 ----
#pragma unroll
  for (int i = 0; i < 2; ++i) {
    int c = tid + i * 256, row = c >> 2, koff = (c & 3) * 8, gk = koff;
    va[i] = (short8){0,0,0,0,0,0,0,0};
    vb[i] = (short8){0,0,0,0,0,0,0,0};
    if (gk + 8 <= K) {
      va[i] = *(const short8*)(Ab + (size_t)(bm0 + row) * K + gk);
      if (bn0 + row < N)
        vb[i] = *(const short8*)(B + (size_t)(bn0 + row) * K + gk);
    }
  }

  for (int k0 = 0; k0 < K; k0 += 32) {
    __syncthreads();
#pragma unroll
    for (int i = 0; i < 2; ++i) {
      int c = tid + i * 256, row = c >> 2, koff = (c & 3) * 8;
      *(short8*)(&As[row * 40 + koff]) = va[i];
      *(short8*)(&Bs[row * 40 + koff]) = vb[i];
    }
    __syncthreads();

    // ---- preload next tile ----
    int kn = k0 + 32;
    if (kn < K) {
#pragma unroll
      for (int i = 0; i < 2; ++i) {
        int c = tid + i * 256, row = c >> 2, koff = (c & 3) * 8, gk = kn + koff;
        va[i] = (short8){0,0,0,0,0,0,0,0};
        vb[i] = (short8){0,0,0,0,0,0,0,0};
        if (gk + 8 <= K) {
          va[i] = *(const short8*)(Ab + (size_t)(bm0 + row) * K + gk);
          if (bn0 + row < N)
            vb[i] = *(const short8*)(B + (size_t)(bn0 + row) * K + gk);
        } else if (gk < K) {
          for (int j = 0; j < K - gk; ++j) {
            va[i][j] = (short)Ab[(size_t)(bm0 + row) * K + gk + j];
            if (bn0 + row < N) vb[i][j] = (short)B[(size_t)(bn0 + row) * K + gk + j];
          }
        }
      }
    }

    short8 af[4], bf[4];
#pragma unroll
    for (int mi = 0; mi < 4; ++mi)
      af[mi] = *(const short8*)(&As[(wm0 + mi * 16 + l16) * 40 + quad * 8]);
#pragma unroll
    for (int ni = 0; ni < 4; ++ni)
      bf[ni] = *(const short8*)(&Bs[(wn0 + ni * 16 + l16) * 40 + quad * 8]);
#pragma unroll
    for (int mi = 0; mi < 4; ++mi)
#pragma unroll
      for (int ni = 0; ni < 4; ++ni)
        acc[mi][ni] = __builtin_amdgcn_mfma_f32_16x16x32_bf16(
            af[mi], bf[ni], acc[mi][ni], 0, 0, 0);
  }

#pragma unroll
  for (int mi = 0; mi < 4; ++mi) {
#pragma unroll
    for (int ni = 0; ni < 4; ++ni) {
      int n = bn0 + wn0 + ni * 16 + l16;
      if (n >= N) continue;
      float bv = bias ? bias[n] : 0.f;
#pragma unroll
      for (int r = 0; r < 4; ++r) {
        int m = bm0 + wm0 + mi * 16 + quad * 4 + r;
        float v = acc[mi][ni][r] + bv;
        if (pack4) {
          outH[((size_t)(n >> 8) * S_LEN + m) * 256 + (n & 255)] =
              __builtin_bit_cast(u16, (_Float16)v);
        } else {
          outF[(size_t)m * N + n] = v;
        }
      }
    }
  }
}

// ---------------------------------------------------------------------------
// Chunked LSTM scan (cell-owned int4 dot8, ping-pong h, 1 barrier/step).
// grid = (NCHUNK, 2 dirs), 256 threads.  Output written as bf16.
// Round-0 configuration restored (proven 116 us): CHUNK_L=64 (2 blocks/CU),
// shuffle-based h repack, no min-waves launch bound.  Rounds 1-4 established:
// weights live in the unified VGPR/AGPR file regardless of hints (neutral);
// capping regs (256,4) spills ~24 B/thread/step to scratch -> 393 MB HBM
// traffic, 2.2x slower.  Do NOT add a min-waves bound here.
// P is GATE-PLANAR: P[(dir*4+g)*S*256 + t*256 + j] f16.
// ---------------------------------------------------------------------------
__global__ __launch_bounds__(256) void lstm_scan(
    const u32* __restrict__ Wq4,    // [2 dirs][1024][32] packed int4 words
    const float* __restrict__ WscL, // [2 dirs][1024]
    const u32* __restrict__ h0q4,   // [4][32]
    const float* __restrict__ h0s,  // [4]
    const float* __restrict__ c0,   // [4][256]
    int row_base,
    const u16* __restrict__ P,      // [2][4][S][256] f16 gate-planar
    u16* __restrict__ Xout)         // [S][512] bf16
{
  const int k    = blockIdx.x;         // chunk
  const int dir  = blockIdx.y;
  const int j    = threadIdx.x;        // cell 0..255
  const int lane = j & 63;

  __shared__ u32 hq[2][32];            // ping-pong int4 h buffers

  const int out_lo = k * CHUNK_L;
  const int out_hi = out_lo + CHUNK_L - 1;
  int tstart, nsteps;
  bool real_init;
  if (dir == 0) {
    int wlo = out_lo - WARM; if (wlo < 0) wlo = 0;
    tstart = wlo;
    nsteps = out_hi - wlo + 1;
    real_init = (wlo == 0);
  } else {
    int whi = out_hi + WARM; if (whi > S_LEN - 1) whi = S_LEN - 1;
    tstart = whi;
    nsteps = whi - out_lo + 1;
    real_init = (whi == S_LEN - 1);
  }
  const int swrite = nsteps - CHUNK_L;

  u32 wi[32], wf[32], wg[32], wo[32];
  {
    const u32* base = Wq4 + (size_t)dir * 1024 * 32;
    const uint4* pi = (const uint4*)(base + (size_t)(j      ) * 32);
    const uint4* pf = (const uint4*)(base + (size_t)(j + 256) * 32);
    const uint4* pg = (const uint4*)(base + (size_t)(j + 512) * 32);
    const uint4* po = (const uint4*)(base + (size_t)(j + 768) * 32);
#pragma unroll
    for (int q = 0; q < 8; ++q) {
      uint4 a = pi[q], b = pf[q], c = pg[q], d = po[q];
      wi[4*q] = a.x; wi[4*q+1] = a.y; wi[4*q+2] = a.z; wi[4*q+3] = a.w;
      wf[4*q] = b.x; wf[4*q+1] = b.y; wf[4*q+2] = b.z; wf[4*q+3] = b.w;
      wg[4*q] = c.x; wg[4*q+1] = c.y; wg[4*q+2] = c.z; wg[4*q+3] = c.w;
      wo[4*q] = d.x; wo[4*q+1] = d.y; wo[4*q+2] = d.z; wo[4*q+3] = d.w;
    }
  }
  const float sci = WscL[dir * 1024 + j];
  const float scf = WscL[dir * 1024 + j + 256];
  const float scg = WscL[dir * 1024 + j + 512];
  const float sco = WscL[dir * 1024 + j + 768];

  float c_state = real_init ? c0[(row_base + dir) * HID + j] : 0.f;
  if (j < 32)
    hq[0][j] = real_init ? h0q4[(size_t)(row_base + dir) * 32 + j] : 0u;
  float hscale = real_init ? h0s[row_base + dir] : (1.f / 7.f);
  __syncthreads();

  const size_t plane = (size_t)S_LEN * 256;
  const ptrdiff_t pstep = dir ? -256 : 256;      // u16 stride per step
  const ptrdiff_t xstep = dir ? -512 : 512;
  const u16* pp = P + (size_t)dir * 4 * plane + (size_t)tstart * 256 + j;
  u16* xp = Xout + (size_t)tstart * 512 + dir * HID + j;

  u16 A0[4], A1[4];
#pragma unroll
  for (int g = 0; g < 4; ++g) A0[g] = pp[g * plane];
  if (nsteps > 1) {
#pragma unroll
    for (int g = 0; g < 4; ++g) A1[g] = pp[pstep + (ptrdiff_t)(g * plane)];
  } else {
#pragma unroll
    for (int g = 0; g < 4; ++g) A1[g] = A0[g];
  }
  const u16* pf2 = pp + 2 * pstep;

  int cur = 0;
  for (int s = 0; s < nsteps; ++s) {
    u16 A2[4];
    if (s < nsteps - 2) {
#pragma unroll
      for (int g = 0; g < 4; ++g) A2[g] = pf2[g * plane];
    } else {
#pragma unroll
      for (int g = 0; g < 4; ++g) A2[g] = A1[g];
    }
    pf2 += pstep;

    u32 hword = hq[cur][lane & 31];
    int ai = 0, af = 0, ag = 0, ao = 0;
#pragma unroll
    for (int q = 0; q < 32; ++q) {
      u32 hs = (u32)__builtin_amdgcn_readlane((int)hword, q);
      ai = sdot8f(wi[q], hs, ai);
      af = sdot8f(wf[q], hs, af);
      ag = sdot8f(wg[q], hs, ag);
      ao = sdot8f(wo[q], hs, ao);
    }
    float gi = sigmoidf_((float)ai * (sci * hscale) + h2f(A0[0]));
    float gf = sigmoidf_((float)af * (scf * hscale) + h2f(A0[1]));
    float gg = tanhf_   ((float)ag * (scg * hscale) + h2f(A0[2]));
    float go = sigmoidf_((float)ao * (sco * hscale) + h2f(A0[3]));
    c_state = gf * c_state + gi * gg;
    float hv = go * tanhf_(c_state);

    int q4 = (int)rintf(hv * 7.f);
    u32 v = ((u32)(q4 & 15)) << (4 * (j & 7));
    v |= (u32)__shfl_xor((int)v, 1, 64);
    v |= (u32)__shfl_xor((int)v, 2, 64);
    v |= (u32)__shfl_xor((int)v, 4, 64);
    if ((j & 7) == 0) hq[cur ^ 1][j >> 3] = v;
    if (s >= swrite) *xp = f2bf(hv);

    hscale = 1.f / 7.f;
#pragma unroll
    for (int g = 0; g < 4; ++g) { A0[g] = A1[g]; A1[g] = A2[g]; }
    xp += xstep;
    __syncthreads();
    cur ^= 1;
  }
}

// ---------------------------------------------------------------------------
// CRF: parallel log-semiring chunk products + fold.
// ---------------------------------------------------------------------------
__global__ __launch_bounds__(192) void crf_chunk(
    const float* __restrict__ feats, const float* __restrict__ trans,
    float* __restrict__ Mc)
{
  __shared__ float tr[144];
  __shared__ float fb[128][12];
  __shared__ float accA[156];
  __shared__ float accB[156];
  const int tid = threadIdx.x;
  const int cb  = blockIdx.x;
  if (tid < 144) tr[tid] = trans[tid];
  for (int i = tid; i < 128 * 12; i += 192)
    fb[i / 12][i % 12] = feats[(size_t)cb * 128 * 12 + i];
  __syncthreads();

  const int ii = tid / 12, jj = tid % 12;
  const bool act = tid < 144;
  float* cur = accA;
  float* nxt = accB;
  if (act) cur[ii * 13 + jj] = tr[ii * 12 + jj] + fb[0][ii];
  __syncthreads();

  for (int t = 1; t < 128; ++t) {
    if (act) {
      float v[12];
      float m = FNEG * 4.f;
#pragma unroll
      for (int kk = 0; kk < 12; ++kk) {
        v[kk] = tr[ii * 12 + kk] + cur[kk * 13 + jj];
        m = fmaxf(m, v[kk]);
      }
      float ssum = 0.f;
#pragma unroll
      for (int kk = 0; kk < 12; ++kk) ssum += __expf(v[kk] - m);
      nxt[ii * 13 + jj] = fb[t][ii] + m + __logf(ssum);
    }
    __syncthreads();
    float* tmp = cur; cur = nxt; nxt = tmp;
  }
  if (act) Mc[(size_t)cb * 144 + ii * 12 + jj] = cur[ii * 13 + jj];
}

__global__ __launch_bounds__(64) void crf_fold(
    const float* __restrict__ Mc, const float* __restrict__ trans,
    float* __restrict__ outp)
{
  __shared__ float fv[12];
  __shared__ float nf[12];
  const int tid = threadIdx.x;
  if (tid < 12) fv[tid] = (tid == TSTART) ? 0.f : FNEG;
  __syncthreads();
  for (int cidx = 0; cidx < 128; ++cidx) {
    if (tid < 12) {
      const float* M = Mc + (size_t)cidx * 144 + tid * 12;
      float v[12];
      float m = FNEG * 4.f;
#pragma unroll
      for (int j = 0; j < 12; ++j) {
        v[j] = M[j] + fv[j];
        m = fmaxf(m, v[j]);
      }
      float s = 0.f;
#pragma unroll
      for (int j = 0; j < 12; ++j) s += __expf(v[j] - m);
      nf[tid] = m + __logf(s);
    }
    __syncthreads();
    if (tid < 12) fv[tid] = nf[tid];
    __syncthreads();
  }
  if (tid == 0) {
    float v[12];
    float m = FNEG * 4.f;
#pragma unroll
    for (int i = 0; i < 12; ++i) {
      v[i] = fv[i] + trans[TSTOP * 12 + i];
      m = fmaxf(m, v[i]);
    }
    float s = 0.f;
#pragma unroll
    for (int i = 0; i < 12; ++i) s += __expf(v[i] - m);
    outp[0] = m + __logf(s);
  }
}

// ---------------------------------------------------------------------------
extern "C" void kernel_launch(void* const* d_in, const int* in_sizes, int n_in,
                              void* d_out, int out_size, void* d_ws, size_t ws_size,
                              hipStream_t stream)
{
  (void)in_sizes; (void)n_in; (void)out_size; (void)ws_size;
  const float* x     = (const float*)d_in[0];
  const float* Wg    = (const float*)d_in[1];
  const float* bg    = (const float*)d_in[2];
  const float* Wn    = (const float*)d_in[3];
  const float* bnn   = (const float*)d_in[4];
  const float* Wl    = (const float*)d_in[5];
  const float* bl    = (const float*)d_in[6];
  const float* Wih0f = (const float*)d_in[7];
  const float* Whh0f = (const float*)d_in[8];
  const float* b0f   = (const float*)d_in[9];
  const float* Wih0b = (const float*)d_in[10];
  const float* Whh0b = (const float*)d_in[11];
  const float* b0b   = (const float*)d_in[12];
  const float* Wih1f = (const float*)d_in[13];
  const float* Whh1f = (const float*)d_in[14];
  const float* b1f   = (const float*)d_in[15];
  const float* Wih1b = (const float*)d_in[16];
  const float* Whh1b = (const float*)d_in[17];
  const float* b1b   = (const float*)d_in[18];
  const float* Wtag  = (const float*)d_in[19];
  const float* btag  = (const float*)d_in[20];
  const float* trans = (const float*)d_in[21];
  const float* h0    = (const float*)d_in[22];
  const float* c0    = (const float*)d_in[23];

  char* ws = (char*)d_ws;
  size_t off = 0;
  auto alloc = [&](size_t bytes) -> void* {
    void* p = ws + off;
    off += (bytes + 255) & ~(size_t)255;
    return p;
  };
  // Pbuf (64 MiB) | X1b (16 MiB bf16)
  u16* Pbuf = (u16*)alloc((size_t)2 * S_LEN * 1024 * 2);
  u16* X1b  = (u16*)alloc((size_t)S_LEN * 512 * 2);

  u16* xb      = (u16*)alloc((size_t)S_LEN * DIM * 2);
  u16* xhw1b   = (u16*)alloc((size_t)S_LEN * DIM * 2);
  u16* xhw2b   = (u16*)alloc((size_t)S_LEN * DIM * 2);
  u16* Wgb     = (u16*)alloc((size_t)2 * DIM * DIM * 2);
  u16* Wnb     = (u16*)alloc((size_t)2 * DIM * DIM * 2);
  u16* Wlb     = (u16*)alloc((size_t)2 * DIM * DIM * 2);
  u16* W0fb    = (u16*)alloc((size_t)1024 * DIM * 2);
  u16* W0bb    = (u16*)alloc((size_t)1024 * DIM * 2);
  u16* W1fb    = (u16*)alloc((size_t)1024 * 512 * 2);
  u16* W1bb    = (u16*)alloc((size_t)1024 * 512 * 2);
  u16* Wtagb   = (u16*)alloc((size_t)NTAG * 512 * 2);
  u32*   Wq4   = (u32*)alloc((size_t)4 * 1024 * 32 * 4);
  float* Wsc   = (float*)alloc((size_t)4096 * 4);
  u32*   h0q4b = (u32*)alloc((size_t)4 * 32 * 4);
  float* h0sb  = (float*)alloc((size_t)4 * 4);
  float* feats = (float*)alloc((size_t)S_LEN * NTAG * 4);
  float* Mc    = (float*)alloc((size_t)128 * 144 * 4);

  // 1) prep: int4 recurrent quant, x + weights -> bf16
  quant_whh4<<<1025, 256, 0, stream>>>(Whh0f, Whh0b, Whh1f, Whh1b, h0,
                                       Wq4, Wsc, h0q4b, h0sb);
  {
    int nx4 = S_LEN * DIM / 4;                       // 1,638,400
    cvt_one<<<(nx4 + 255) / 256, 256, 0, stream>>>(x, xb, nx4);
    int nHW = 2 * DIM * DIM / 4;
    int nP0 = 1024 * DIM / 4;
    int nP1 = 1024 * 512 / 4;
    int nTG = NTAG * 512 / 4;
    dim3 gC((131072 + 255) / 256, NCVT);
    cvt_multi<<<gC, 256, 0, stream>>>(Wg, Wn, Wl, Wih0f, Wih0b, Wih1f, Wih1b, Wtag,
                                      Wgb, Wnb, Wlb, W0fb, W0bb, W1fb, W1bb, Wtagb,
                                      nHW, nHW, nHW, nP0, nP0, nP1, nP1, nTG);
  }

  // 2) highway x2 (fused 3-GEMM + combine)
  dim3 gHW(S_LEN / 128, (DIM + 63) / 64);           // 128 x 7
  hw_fused<<<gHW, 256, 0, stream>>>(xb, Wgb, Wnb, Wlb, bg, bnn, bl, xhw1b);
  hw_fused<<<gHW, 256, 0, stream>>>(xhw1b, Wgb + 160000, Wnb + 160000,
                                    Wlb + 160000, bg + 400, bnn + 400, bl + 400,
                                    xhw2b);

  // 3) layer-0 input projections (z=2, f16 gate-planar)
  dim3 gP(S_LEN / 128, 1024 / 128, 2);
  gemm_multi<<<gP, 256, 0, stream>>>(xhw2b, W0fb, W0bb, b0f, b0b,
                                     nullptr, nullptr, Pbuf, 1,
                                     S_LEN, 1024, DIM);

  // 4) layer-0 bidirectional chunked scan -> X1b [S,512] bf16
  dim3 gS(NCHUNK, 2);
  lstm_scan<<<gS, 256, 0, stream>>>(Wq4, Wsc, h0q4b, h0sb, c0, 0, Pbuf, X1b);

  // 5) layer-1 input projections
  gemm_multi<<<gP, 256, 0, stream>>>(X1b, W1fb, W1bb, b1f, b1b,
                                     nullptr, nullptr, Pbuf, 1,
                                     S_LEN, 1024, 512);

  // 6) layer-1 chunked scan -> X1b reused as lstm_out (bf16)
  lstm_scan<<<gS, 256, 0, stream>>>(Wq4 + (size_t)2 * 1024 * 32, Wsc + 2048,
                                    h0q4b, h0sb, c0, 2, Pbuf, X1b);

  // 7) tag projection -> feats [S,12]
  dim3 gT(S_LEN / 128, 1, 1);
  gemm_multi<<<gT, 256, 0, stream>>>(X1b, Wtagb, nullptr, btag, nullptr,
                                     feats, nullptr, nullptr, 0,
                                     S_LEN, NTAG, 512);

  // 8) CRF log-partition
  crf_chunk<<<128, 192, 0, stream>>>(feats, trans, Mc);
  crf_fold<<<1, 64, 0, stream>>>(Mc, trans, (float*)d_out);
}

// Round 7
// 650.111 us; speedup vs baseline: 1.4727x; 1.0405x over previous
//
#include <hip/hip_runtime.h>
#include <cstddef>

#define S_LEN 16384
#define DIM   400
#define HID   256
#define NTAG  12
#define TSTART 10
#define TSTOP  11
#define FNEG  -10000.0f

// chunked scan: 256 output chunks of 64 steps, 16 warmup steps
#define CHUNK_L 64
#define NCHUNK  256
#define WARM    16

typedef unsigned int   u32;
typedef unsigned short u16;
typedef _Float16 half2_t __attribute__((ext_vector_type(2)));
typedef short    short8 __attribute__((ext_vector_type(8)));
typedef float    f32x4  __attribute__((ext_vector_type(4)));
typedef unsigned short u16x4 __attribute__((ext_vector_type(4)));

__device__ __forceinline__ int sdot8f(u32 a, u32 b, int acc) {
#if defined(__has_builtin) && __has_builtin(__builtin_amdgcn_sdot8)
  return __builtin_amdgcn_sdot8((int)a, (int)b, acc, false);
#else
  #pragma unroll
  for (int i = 0; i < 8; ++i) {
    int ai = ((int)(a << (28 - 4 * i))) >> 28;
    int bi = ((int)(b << (28 - 4 * i))) >> 28;
    acc += ai * bi;
  }
  return acc;
#endif
}

__device__ __forceinline__ float sigmoidf_(float x) {
  return 1.0f / (1.0f + __expf(-x));
}
__device__ __forceinline__ float tanhf_(float x) {
  float e = __expf(2.0f * x);
  return 1.0f - 2.0f / (e + 1.0f);
}
__device__ __forceinline__ u16 f2bf(float f) {   // f32 -> bf16 RNE
  u32 u = __builtin_bit_cast(u32, f);
  u = u + 0x7FFFu + ((u >> 16) & 1u);
  return (u16)(u >> 16);
}

// ---------------------------------------------------------------------------
// Simple f32 -> bf16 convert (for x)
// ---------------------------------------------------------------------------
__global__ __launch_bounds__(256) void cvt_one(
    const float* __restrict__ in, u16* __restrict__ out, int n4)
{
  int i = blockIdx.x * 256 + threadIdx.x;
  if (i >= n4) return;
  float4 v = *(const float4*)(in + (size_t)i * 4);
  u16x4 o;
  o.x = f2bf(v.x); o.y = f2bf(v.y); o.z = f2bf(v.z); o.w = f2bf(v.w);
  *(u16x4*)(out + (size_t)i * 4) = o;
}

// ---------------------------------------------------------------------------
// Batched f32 -> bf16 weight convert.  blockIdx.y selects slice.
// ---------------------------------------------------------------------------
#define NCVT 8
__global__ __launch_bounds__(256) void cvt_multi(
    const float* __restrict__ s0, const float* __restrict__ s1,
    const float* __restrict__ s2, const float* __restrict__ s3,
    const float* __restrict__ s4, const float* __restrict__ s5,
    const float* __restrict__ s6, const float* __restrict__ s7,
    u16* __restrict__ d0, u16* __restrict__ d1,
    u16* __restrict__ d2, u16* __restrict__ d3,
    u16* __restrict__ d4, u16* __restrict__ d5,
    u16* __restrict__ d6, u16* __restrict__ d7,
    int n40, int n41, int n42, int n43, int n44, int n45, int n46, int n47)
{
  const int z = blockIdx.y;
  const float* src = (z==0)?s0:(z==1)?s1:(z==2)?s2:(z==3)?s3:(z==4)?s4:(z==5)?s5:(z==6)?s6:s7;
  u16* dst = (z==0)?d0:(z==1)?d1:(z==2)?d2:(z==3)?d3:(z==4)?d4:(z==5)?d5:(z==6)?d6:d7;
  const int n4 = (z==0)?n40:(z==1)?n41:(z==2)?n42:(z==3)?n43:(z==4)?n44:(z==5)?n45:(z==6)?n46:n47;
  int i = blockIdx.x * 256 + threadIdx.x;
  if (i >= n4) return;
  float4 v = *(const float4*)(src + (size_t)i * 4);
  u16x4 o;
  o.x = f2bf(v.x); o.y = f2bf(v.y); o.z = f2bf(v.z); o.w = f2bf(v.w);
  *(u16x4*)(dst + (size_t)i * 4) = o;
}

// ---------------------------------------------------------------------------
// Quantize Whh rows (4 mats x 1024 rows x 256) and h0 (4 rows x 256) to INT4
// with per-row scale.  One wave per row.
// ---------------------------------------------------------------------------
__global__ __launch_bounds__(256) void quant_whh4(
    const float* __restrict__ W0f, const float* __restrict__ W0b,
    const float* __restrict__ W1f, const float* __restrict__ W1b,
    const float* __restrict__ h0,
    u32* __restrict__ Wq4, float* __restrict__ Wsc,
    u32* __restrict__ h0q4, float* __restrict__ h0s)
{
  const int wave = threadIdx.x >> 6;
  const int lane = threadIdx.x & 63;
  const int row  = blockIdx.x * 4 + wave;
  if (row >= 4100) return;
  const float* src;
  if (row < 4096) {
    int mat = row >> 10, r = row & 1023;
    const float* W = (mat == 0) ? W0f : (mat == 1) ? W0b : (mat == 2) ? W1f : W1b;
    src = W + (size_t)r * HID;
  } else {
    src = h0 + (size_t)(row - 4096) * HID;
  }
  float4 v = *(const float4*)(src + lane * 4);
  float m = fmaxf(fmaxf(fabsf(v.x), fabsf(v.y)), fmaxf(fabsf(v.z), fabsf(v.w)));
#pragma unroll
  for (int off = 32; off; off >>= 1) m = fmaxf(m, __shfl_xor(m, off, 64));
  float inv   = (m > 0.f) ? 7.f / m : 0.f;
  float scale = (m > 0.f) ? m / 7.f : 0.f;
  int q0 = (int)rintf(v.x * inv);
  int q1 = (int)rintf(v.y * inv);
  int q2 = (int)rintf(v.z * inv);
  int q3 = (int)rintf(v.w * inv);
  u32 nib16 = (u32)(q0 & 15) | ((u32)(q1 & 15) << 4)
            | ((u32)(q2 & 15) << 8) | ((u32)(q3 & 15) << 12);
  u32 other = (u32)__shfl_xor((int)nib16, 1, 64);
  if ((lane & 1) == 0) {
    u32 word = nib16 | (other << 16);
    if (row < 4096) Wq4[(size_t)row * 32 + (lane >> 1)] = word;
    else            h0q4[(size_t)(row - 4096) * 32 + (lane >> 1)] = word;
  }
  if (lane == 0) {
    if (row < 4096) Wsc[row] = scale;
    else            h0s[row - 4096] = scale;
  }
}

// ---------------------------------------------------------------------------
// Fused highway layer (MFMA): computes G/N/L = A.W{g,n,l}^T + b in one pass
// (3 accumulators sharing the A tile), applies the highway combine in the
// epilogue, writes bf16.  Block tile 128(M) x 64(N); 4 waves 2x2, per-wave
// 64x32.  K-step 32, register-pipelined staging.  A bf16 [M,400]; W bf16
// [400,400] row-major (3 mats); out bf16 [M,400].
// ---------------------------------------------------------------------------
__global__ __launch_bounds__(256) void hw_fused(
    const u16* __restrict__ A,
    const u16* __restrict__ Wgb, const u16* __restrict__ Wnb,
    const u16* __restrict__ Wlb,
    const float* __restrict__ bg, const float* __restrict__ bnn,
    const float* __restrict__ bl,
    u16* __restrict__ outb)
{
  __shared__ u16 As[128 * 40];            // 10.0 KB
  __shared__ u16 Bs[3 * 64 * 40];         // 15.0 KB
  const int tid  = threadIdx.x;
  const int bm0  = blockIdx.x * 128;
  const int bn0  = blockIdx.y * 64;
  const int w    = tid >> 6;
  const int lane = tid & 63;
  const int quad = lane >> 4;
  const int l16  = lane & 15;
  const int wm0  = (w >> 1) * 64;
  const int wn0  = (w & 1) * 32;
  const int K = DIM, N = DIM;

  f32x4 acc[3][4][2];
#pragma unroll
  for (int z = 0; z < 3; ++z)
#pragma unroll
    for (int i = 0; i < 4; ++i)
#pragma unroll
      for (int j = 0; j < 2; ++j) acc[z][i][j] = (f32x4){0.f, 0.f, 0.f, 0.f};

  short8 va[2], vb[3];
  // ---- preload k0 = 0 ----
#pragma unroll
  for (int i = 0; i < 2; ++i) {
    int c = tid + i * 256, row = c >> 2, koff = (c & 3) * 8, gk = koff;
    va[i] = (short8){0,0,0,0,0,0,0,0};
    if (gk + 8 <= K)
      va[i] = *(const short8*)(A + (size_t)(bm0 + row) * K + gk);
  }
#pragma unroll
  for (int i = 0; i < 3; ++i) {
    int c = tid + i * 256, z = c >> 8, r = (c >> 2) & 63, koff = (c & 3) * 8;
    int gn = bn0 + r, gk = koff;
    const u16* W = (z == 0) ? Wgb : (z == 1) ? Wnb : Wlb;
    vb[i] = (short8){0,0,0,0,0,0,0,0};
    if (gn < N && gk + 8 <= K)
      vb[i] = *(const short8*)(W + (size_t)gn * K + gk);
  }

  for (int k0 = 0; k0 < K; k0 += 32) {
    __syncthreads();
#pragma unroll
    for (int i = 0; i < 2; ++i) {
      int c = tid + i * 256, row = c >> 2, koff = (c & 3) * 8;
      *(short8*)(&As[row * 40 + koff]) = va[i];
    }
#pragma unroll
    for (int i = 0; i < 3; ++i) {
      int c = tid + i * 256, z = c >> 8, r = (c >> 2) & 63, koff = (c & 3) * 8;
      *(short8*)(&Bs[z * 2560 + r * 40 + koff]) = vb[i];
    }
    __syncthreads();

    // ---- preload next tile while MFMAs run ----
    int kn = k0 + 32;
    if (kn < K) {
#pragma unroll
      for (int i = 0; i < 2; ++i) {
        int c = tid + i * 256, row = c >> 2, koff = (c & 3) * 8, gk = kn + koff;
        va[i] = (short8){0,0,0,0,0,0,0,0};
        if (gk + 8 <= K)
          va[i] = *(const short8*)(A + (size_t)(bm0 + row) * K + gk);
        else if (gk < K)
          for (int j = 0; j < K - gk; ++j) va[i][j] = (short)A[(size_t)(bm0 + row) * K + gk + j];
      }
#pragma unroll
      for (int i = 0; i < 3; ++i) {
        int c = tid + i * 256, z = c >> 8, r = (c >> 2) & 63, koff = (c & 3) * 8;
        int gn = bn0 + r, gk = kn + koff;
        const u16* W = (z == 0) ? Wgb : (z == 1) ? Wnb : Wlb;
        vb[i] = (short8){0,0,0,0,0,0,0,0};
        if (gn < N) {
          if (gk + 8 <= K)
            vb[i] = *(const short8*)(W + (size_t)gn * K + gk);
          else if (gk < K)
            for (int j = 0; j < K - gk; ++j) vb[i][j] = (short)W[(size_t)gn * K + gk + j];
        }
      }
    }

    short8 af[4];
#pragma unroll
    for (int mi = 0; mi < 4; ++mi)
      af[mi] = *(const short8*)(&As[(wm0 + mi * 16 + l16) * 40 + quad * 8]);
#pragma unroll
    for (int z = 0; z < 3; ++z) {
      short8 bf0 = *(const short8*)(&Bs[z * 2560 + (wn0 + l16) * 40 + quad * 8]);
      short8 bf1 = *(const short8*)(&Bs[z * 2560 + (wn0 + 16 + l16) * 40 + quad * 8]);
#pragma unroll
      for (int mi = 0; mi < 4; ++mi) {
        acc[z][mi][0] = __builtin_amdgcn_mfma_f32_16x16x32_bf16(af[mi], bf0, acc[z][mi][0], 0, 0, 0);
        acc[z][mi][1] = __builtin_amdgcn_mfma_f32_16x16x32_bf16(af[mi], bf1, acc[z][mi][1], 0, 0, 0);
      }
    }
  }

  // ---- epilogue: highway combine -> bf16 ----
#pragma unroll
  for (int ni = 0; ni < 2; ++ni) {
    int n = bn0 + wn0 + ni * 16 + l16;
    if (n >= N) continue;
    float bgv = bg[n], bnv = bnn[n], blv = bl[n];
#pragma unroll
    for (int mi = 0; mi < 4; ++mi) {
#pragma unroll
      for (int r = 0; r < 4; ++r) {
        int m = bm0 + wm0 + mi * 16 + quad * 4 + r;
        float gv = acc[0][mi][ni][r] + bgv;
        float nv = acc[1][mi][ni][r] + bnv;
        float lv = acc[2][mi][ni][r] + blv;
        float g = sigmoidf_(gv);
        float v = g * fmaxf(nv, 0.f) + (1.f - g) * lv;
        outb[(size_t)m * N + n] = f2bf(v);
      }
    }
  }
}

// ---------------------------------------------------------------------------
// bf16 MFMA GEMM, z-batched, register-pipelined.  C = A.B^T + bias.
// A bf16 [M,K]; B bf16 [N,K]; z selects {B, bias, outF}.
// pack4 (N==1024): B rows are staged through the permutation
//   perm(r) = (r&3)*256 + (r>>2)      (cell-major gate order)
// so output column n == cell*4 + gate and the epilogue writes f16 to
//   oH[z*S*1024 + m*1024 + n]  -- fully contiguous (full 32B sectors; round-6
// measured ~40 us gain vs the scattered [cell][4] store, and this layout is
// bit-identical to the scan's proven uint2-per-cell read).  Bias is gathered
// through the same perm.  Tile 128x128, 4 waves 2x2, K-step 32, LDS stride 40.
// ---------------------------------------------------------------------------
__global__ __launch_bounds__(256) void gemm_multi(
    const u16* __restrict__ Ab,
    const u16* __restrict__ B0, const u16* __restrict__ B1,
    const float* __restrict__ bias0, const float* __restrict__ bias1,
    float* __restrict__ oF0, float* __restrict__ oF1,
    u16* __restrict__ oH, int pack4,
    int M, int N, int K)
{
  __shared__ u16 As[128 * 40];
  __shared__ u16 Bs[128 * 40];
  const int z = blockIdx.z;
  const u16* B      = (z == 0) ? B0 : B1;
  const float* bias = (z == 0) ? bias0 : bias1;
  float* outF       = (z == 0) ? oF0 : oF1;
  u16* outH         = pack4 ? (oH + (size_t)z * S_LEN * 1024) : nullptr;

  const int tid  = threadIdx.x;
  const int bm0  = blockIdx.x * 128;
  const int bn0  = blockIdx.y * 128;
  const int w    = tid >> 6;
  const int lane = tid & 63;
  const int quad = lane >> 4;
  const int l16  = lane & 15;
  const int wm0  = (w >> 1) * 64;
  const int wn0  = (w & 1) * 64;

  f32x4 acc[4][4];
#pragma unroll
  for (int i = 0; i < 4; ++i)
#pragma unroll
    for (int j = 0; j < 4; ++j) acc[i][j] = (f32x4){0.f, 0.f, 0.f, 0.f};

  short8 va[2], vb[2];
  // ---- preload k0 = 0 ----
#pragma unroll
  for (int i = 0; i < 2; ++i) {
    int c = tid + i * 256, row = c >> 2, koff = (c & 3) * 8, gk = koff;
    int gn = bn0 + row;
    int brow = pack4 ? ((gn & 3) * 256 + (gn >> 2)) : gn;
    va[i] = (short8){0,0,0,0,0,0,0,0};
    vb[i] = (short8){0,0,0,0,0,0,0,0};
    if (gk + 8 <= K) {
      va[i] = *(const short8*)(Ab + (size_t)(bm0 + row) * K + gk);
      if (gn < N)
        vb[i] = *(const short8*)(B + (size_t)brow * K + gk);
    }
  }

  for (int k0 = 0; k0 < K; k0 += 32) {
    __syncthreads();
#pragma unroll
    for (int i = 0; i < 2; ++i) {
      int c = tid + i * 256, row = c >> 2, koff = (c & 3) * 8;
      *(short8*)(&As[row * 40 + koff]) = va[i];
      *(short8*)(&Bs[row * 40 + koff]) = vb[i];
    }
    __syncthreads();

    // ---- preload next tile ----
    int kn = k0 + 32;
    if (kn < K) {
#pragma unroll
      for (int i = 0; i < 2; ++i) {
        int c = tid + i * 256, row = c >> 2, koff = (c & 3) * 8, gk = kn + koff;
        int gn = bn0 + row;
        int brow = pack4 ? ((gn & 3) * 256 + (gn >> 2)) : gn;
        va[i] = (short8){0,0,0,0,0,0,0,0};
        vb[i] = (short8){0,0,0,0,0,0,0,0};
        if (gk + 8 <= K) {
          va[i] = *(const short8*)(Ab + (size_t)(bm0 + row) * K + gk);
          if (gn < N)
            vb[i] = *(const short8*)(B + (size_t)brow * K + gk);
        } else if (gk < K) {
          for (int j = 0; j < K - gk; ++j) {
            va[i][j] = (short)Ab[(size_t)(bm0 + row) * K + gk + j];
            if (gn < N) vb[i][j] = (short)B[(size_t)brow * K + gk + j];
          }
        }
      }
    }

    short8 af[4], bf[4];
#pragma unroll
    for (int mi = 0; mi < 4; ++mi)
      af[mi] = *(const short8*)(&As[(wm0 + mi * 16 + l16) * 40 + quad * 8]);
#pragma unroll
    for (int ni = 0; ni < 4; ++ni)
      bf[ni] = *(const short8*)(&Bs[(wn0 + ni * 16 + l16) * 40 + quad * 8]);
#pragma unroll
    for (int mi = 0; mi < 4; ++mi)
#pragma unroll
      for (int ni = 0; ni < 4; ++ni)
        acc[mi][ni] = __builtin_amdgcn_mfma_f32_16x16x32_bf16(
            af[mi], bf[ni], acc[mi][ni], 0, 0, 0);
  }

#pragma unroll
  for (int mi = 0; mi < 4; ++mi) {
#pragma unroll
    for (int ni = 0; ni < 4; ++ni) {
      int n = bn0 + wn0 + ni * 16 + l16;
      if (n >= N) continue;
      float bv = 0.f;
      if (bias) bv = pack4 ? bias[(n & 3) * 256 + (n >> 2)] : bias[n];
#pragma unroll
      for (int r = 0; r < 4; ++r) {
        int m = bm0 + wm0 + mi * 16 + quad * 4 + r;
        float v = acc[mi][ni][r] + bv;
        if (pack4) {
          outH[(size_t)m * 1024 + n] = __builtin_bit_cast(u16, (_Float16)v);
        } else {
          outF[(size_t)m * N + n] = v;
        }
      }
    }
  }
}

// ---------------------------------------------------------------------------
// Chunked LSTM scan (cell-owned int4 dot8, ping-pong h, 1 barrier/step).
// grid = (NCHUNK, 2 dirs), 256 threads.  Output written as bf16.
// EXACT round-0/round-2 configuration (proven 116 us): CHUNK_L=64
// (2 blocks/CU), uint2 P read ([S][256 cells][4 gates] f16), shuffle-based
// h repack, plain __launch_bounds__(256).  Rounds 1-4 established: weights
// live in the unified VGPR/AGPR file regardless of hints (hint-neutral);
// capping regs (256,4) spills to scratch -> 393 MB HBM, 2.2x slower; planar
// per-gate P reads (4 scalar ushort streams) cost +450 cyc/step (round 6).
// Do NOT add a min-waves bound; do NOT split the P read.
// ---------------------------------------------------------------------------
__global__ __launch_bounds__(256) void lstm_scan(
    const u32* __restrict__ Wq4,    // [2 dirs][1024][32] packed int4 words
    const float* __restrict__ WscL, // [2 dirs][1024]
    const u32* __restrict__ h0q4,   // [4][32]
    const float* __restrict__ h0s,  // [4]
    const float* __restrict__ c0,   // [4][256]
    int row_base,
    const u16* __restrict__ P,      // [2][S][256][4] f16 cell-major gates
    u16* __restrict__ Xout)         // [S][512] bf16
{
  const int k    = blockIdx.x;         // chunk
  const int dir  = blockIdx.y;
  const int j    = threadIdx.x;        // cell 0..255
  const int lane = j & 63;

  __shared__ u32 hq[2][32];            // ping-pong int4 h buffers

  const int out_lo = k * CHUNK_L;
  const int out_hi = out_lo + CHUNK_L - 1;
  int tstart, nsteps;
  bool real_init;
  if (dir == 0) {
    int wlo = out_lo - WARM; if (wlo < 0) wlo = 0;
    tstart = wlo;
    nsteps = out_hi - wlo + 1;
    real_init = (wlo == 0);
  } else {
    int whi = out_hi + WARM; if (whi > S_LEN - 1) whi = S_LEN - 1;
    tstart = whi;
    nsteps = whi - out_lo + 1;
    real_init = (whi == S_LEN - 1);
  }
  const int swrite = nsteps - CHUNK_L;

  u32 wi[32], wf[32], wg[32], wo[32];
  {
    const u32* base = Wq4 + (size_t)dir * 1024 * 32;
    const uint4* pi = (const uint4*)(base + (size_t)(j      ) * 32);
    const uint4* pf = (const uint4*)(base + (size_t)(j + 256) * 32);
    const uint4* pg = (const uint4*)(base + (size_t)(j + 512) * 32);
    const uint4* po = (const uint4*)(base + (size_t)(j + 768) * 32);
#pragma unroll
    for (int q = 0; q < 8; ++q) {
      uint4 a = pi[q], b = pf[q], c = pg[q], d = po[q];
      wi[4*q] = a.x; wi[4*q+1] = a.y; wi[4*q+2] = a.z; wi[4*q+3] = a.w;
      wf[4*q] = b.x; wf[4*q+1] = b.y; wf[4*q+2] = b.z; wf[4*q+3] = b.w;
      wg[4*q] = c.x; wg[4*q+1] = c.y; wg[4*q+2] = c.z; wg[4*q+3] = c.w;
      wo[4*q] = d.x; wo[4*q+1] = d.y; wo[4*q+2] = d.z; wo[4*q+3] = d.w;
    }
  }
  const float sci = WscL[dir * 1024 + j];
  const float scf = WscL[dir * 1024 + j + 256];
  const float scg = WscL[dir * 1024 + j + 512];
  const float sco = WscL[dir * 1024 + j + 768];

  float c_state = real_init ? c0[(row_base + dir) * HID + j] : 0.f;
  if (j < 32)
    hq[0][j] = real_init ? h0q4[(size_t)(row_base + dir) * 32 + j] : 0u;
  float hscale = real_init ? h0s[row_base + dir] : (1.f / 7.f);
  __syncthreads();

  const ptrdiff_t pstep = dir ? -1024 : 1024;
  const ptrdiff_t xstep = dir ? -512 : 512;
  const u16* pp = P + (size_t)dir * S_LEN * 1024 + (size_t)tstart * 1024 + j * 4;
  u16* xp = Xout + (size_t)tstart * 512 + dir * HID + j;

  uint2 p0 = *(const uint2*)pp;
  uint2 p1 = (nsteps > 1) ? *(const uint2*)(pp + pstep) : p0;
  const u16* pf2 = pp + 2 * pstep;

  int cur = 0;
  for (int s = 0; s < nsteps; ++s) {
    uint2 p2 = (s < nsteps - 2) ? *(const uint2*)pf2 : p1;
    pf2 += pstep;

    u32 hword = hq[cur][lane & 31];
    int ai = 0, af = 0, ag = 0, ao = 0;
#pragma unroll
    for (int q = 0; q < 32; ++q) {
      u32 hs = (u32)__builtin_amdgcn_readlane((int)hword, q);
      ai = sdot8f(wi[q], hs, ai);
      af = sdot8f(wf[q], hs, af);
      ag = sdot8f(wg[q], hs, ag);
      ao = sdot8f(wo[q], hs, ao);
    }
    half2_t pif = __builtin_bit_cast(half2_t, p0.x);
    half2_t pgo = __builtin_bit_cast(half2_t, p0.y);
    float gi = sigmoidf_((float)ai * (sci * hscale) + (float)pif[0]);
    float gf = sigmoidf_((float)af * (scf * hscale) + (float)pif[1]);
    float gg = tanhf_   ((float)ag * (scg * hscale) + (float)pgo[0]);
    float go = sigmoidf_((float)ao * (sco * hscale) + (float)pgo[1]);
    c_state = gf * c_state + gi * gg;
    float hv = go * tanhf_(c_state);

    int q4 = (int)rintf(hv * 7.f);
    u32 v = ((u32)(q4 & 15)) << (4 * (j & 7));
    v |= (u32)__shfl_xor((int)v, 1, 64);
    v |= (u32)__shfl_xor((int)v, 2, 64);
    v |= (u32)__shfl_xor((int)v, 4, 64);
    if ((j & 7) == 0) hq[cur ^ 1][j >> 3] = v;
    if (s >= swrite) *xp = f2bf(hv);

    hscale = 1.f / 7.f;
    p0 = p1; p1 = p2;
    xp += xstep;
    __syncthreads();
    cur ^= 1;
  }
}

// ---------------------------------------------------------------------------
// CRF: parallel log-semiring chunk products + fold.
// ---------------------------------------------------------------------------
__global__ __launch_bounds__(192) void crf_chunk(
    const float* __restrict__ feats, const float* __restrict__ trans,
    float* __restrict__ Mc)
{
  __shared__ float tr[144];
  __shared__ float fb[128][12];
  __shared__ float accA[156];
  __shared__ float accB[156];
  const int tid = threadIdx.x;
  const int cb  = blockIdx.x;
  if (tid < 144) tr[tid] = trans[tid];
  for (int i = tid; i < 128 * 12; i += 192)
    fb[i / 12][i % 12] = feats[(size_t)cb * 128 * 12 + i];
  __syncthreads();

  const int ii = tid / 12, jj = tid % 12;
  const bool act = tid < 144;
  float* cur = accA;
  float* nxt = accB;
  if (act) cur[ii * 13 + jj] = tr[ii * 12 + jj] + fb[0][ii];
  __syncthreads();

  for (int t = 1; t < 128; ++t) {
    if (act) {
      float v[12];
      float m = FNEG * 4.f;
#pragma unroll
      for (int kk = 0; kk < 12; ++kk) {
        v[kk] = tr[ii * 12 + kk] + cur[kk * 13 + jj];
        m = fmaxf(m, v[kk]);
      }
      float ssum = 0.f;
#pragma unroll
      for (int kk = 0; kk < 12; ++kk) ssum += __expf(v[kk] - m);
      nxt[ii * 13 + jj] = fb[t][ii] + m + __logf(ssum);
    }
    __syncthreads();
    float* tmp = cur; cur = nxt; nxt = tmp;
  }
  if (act) Mc[(size_t)cb * 144 + ii * 12 + jj] = cur[ii * 13 + jj];
}

__global__ __launch_bounds__(64) void crf_fold(
    const float* __restrict__ Mc, const float* __restrict__ trans,
    float* __restrict__ outp)
{
  __shared__ float fv[12];
  __shared__ float nf[12];
  const int tid = threadIdx.x;
  if (tid < 12) fv[tid] = (tid == TSTART) ? 0.f : FNEG;
  __syncthreads();
  for (int cidx = 0; cidx < 128; ++cidx) {
    if (tid < 12) {
      const float* M = Mc + (size_t)cidx * 144 + tid * 12;
      float v[12];
      float m = FNEG * 4.f;
#pragma unroll
      for (int j = 0; j < 12; ++j) {
        v[j] = M[j] + fv[j];
        m = fmaxf(m, v[j]);
      }
      float s = 0.f;
#pragma unroll
      for (int j = 0; j < 12; ++j) s += __expf(v[j] - m);
      nf[tid] = m + __logf(s);
    }
    __syncthreads();
    if (tid < 12) fv[tid] = nf[tid];
    __syncthreads();
  }
  if (tid == 0) {
    float v[12];
    float m = FNEG * 4.f;
#pragma unroll
    for (int i = 0; i < 12; ++i) {
      v[i] = fv[i] + trans[TSTOP * 12 + i];
      m = fmaxf(m, v[i]);
    }
    float s = 0.f;
#pragma unroll
    for (int i = 0; i < 12; ++i) s += __expf(v[i] - m);
    outp[0] = m + __logf(s);
  }
}

// ---------------------------------------------------------------------------
extern "C" void kernel_launch(void* const* d_in, const int* in_sizes, int n_in,
                              void* d_out, int out_size, void* d_ws, size_t ws_size,
                              hipStream_t stream)
{
  (void)in_sizes; (void)n_in; (void)out_size; (void)ws_size;
  const float* x     = (const float*)d_in[0];
  const float* Wg    = (const float*)d_in[1];
  const float* bg    = (const float*)d_in[2];
  const float* Wn    = (const float*)d_in[3];
  const float* bnn   = (const float*)d_in[4];
  const float* Wl    = (const float*)d_in[5];
  const float* bl    = (const float*)d_in[6];
  const float* Wih0f = (const float*)d_in[7];
  const float* Whh0f = (const float*)d_in[8];
  const float* b0f   = (const float*)d_in[9];
  const float* Wih0b = (const float*)d_in[10];
  const float* Whh0b = (const float*)d_in[11];
  const float* b0b   = (const float*)d_in[12];
  const float* Wih1f = (const float*)d_in[13];
  const float* Whh1f = (const float*)d_in[14];
  const float* b1f   = (const float*)d_in[15];
  const float* Wih1b = (const float*)d_in[16];
  const float* Whh1b = (const float*)d_in[17];
  const float* b1b   = (const float*)d_in[18];
  const float* Wtag  = (const float*)d_in[19];
  const float* btag  = (const float*)d_in[20];
  const float* trans = (const float*)d_in[21];
  const float* h0    = (const float*)d_in[22];
  const float* c0    = (const float*)d_in[23];

  char* ws = (char*)d_ws;
  size_t off = 0;
  auto alloc = [&](size_t bytes) -> void* {
    void* p = ws + off;
    off += (bytes + 255) & ~(size_t)255;
    return p;
  };
  // Pbuf (64 MiB) | X1b (16 MiB bf16)
  u16* Pbuf = (u16*)alloc((size_t)2 * S_LEN * 1024 * 2);
  u16* X1b  = (u16*)alloc((size_t)S_LEN * 512 * 2);

  u16* xb      = (u16*)alloc((size_t)S_LEN * DIM * 2);
  u16* xhw1b   = (u16*)alloc((size_t)S_LEN * DIM * 2);
  u16* xhw2b   = (u16*)alloc((size_t)S_LEN * DIM * 2);
  u16* Wgb     = (u16*)alloc((size_t)2 * DIM * DIM * 2);
  u16* Wnb     = (u16*)alloc((size_t)2 * DIM * DIM * 2);
  u16* Wlb     = (u16*)alloc((size_t)2 * DIM * DIM * 2);
  u16* W0fb    = (u16*)alloc((size_t)1024 * DIM * 2);
  u16* W0bb    = (u16*)alloc((size_t)1024 * DIM * 2);
  u16* W1fb    = (u16*)alloc((size_t)1024 * 512 * 2);
  u16* W1bb    = (u16*)alloc((size_t)1024 * 512 * 2);
  u16* Wtagb   = (u16*)alloc((size_t)NTAG * 512 * 2);
  u32*   Wq4   = (u32*)alloc((size_t)4 * 1024 * 32 * 4);
  float* Wsc   = (float*)alloc((size_t)4096 * 4);
  u32*   h0q4b = (u32*)alloc((size_t)4 * 32 * 4);
  float* h0sb  = (float*)alloc((size_t)4 * 4);
  float* feats = (float*)alloc((size_t)S_LEN * NTAG * 4);
  float* Mc    = (float*)alloc((size_t)128 * 144 * 4);

  // 1) prep: int4 recurrent quant, x + weights -> bf16
  quant_whh4<<<1025, 256, 0, stream>>>(Whh0f, Whh0b, Whh1f, Whh1b, h0,
                                       Wq4, Wsc, h0q4b, h0sb);
  {
    int nx4 = S_LEN * DIM / 4;                       // 1,638,400
    cvt_one<<<(nx4 + 255) / 256, 256, 0, stream>>>(x, xb, nx4);
    int nHW = 2 * DIM * DIM / 4;
    int nP0 = 1024 * DIM / 4;
    int nP1 = 1024 * 512 / 4;
    int nTG = NTAG * 512 / 4;
    dim3 gC((131072 + 255) / 256, NCVT);
    cvt_multi<<<gC, 256, 0, stream>>>(Wg, Wn, Wl, Wih0f, Wih0b, Wih1f, Wih1b, Wtag,
                                      Wgb, Wnb, Wlb, W0fb, W0bb, W1fb, W1bb, Wtagb,
                                      nHW, nHW, nHW, nP0, nP0, nP1, nP1, nTG);
  }

  // 2) highway x2 (fused 3-GEMM + combine)
  dim3 gHW(S_LEN / 128, (DIM + 63) / 64);           // 128 x 7
  hw_fused<<<gHW, 256, 0, stream>>>(xb, Wgb, Wnb, Wlb, bg, bnn, bl, xhw1b);
  hw_fused<<<gHW, 256, 0, stream>>>(xhw1b, Wgb + 160000, Wnb + 160000,
                                    Wlb + 160000, bg + 400, bnn + 400, bl + 400,
                                    xhw2b);

  // 3) layer-0 input projections (z=2, f16 cell-major via permuted staging)
  dim3 gP(S_LEN / 128, 1024 / 128, 2);
  gemm_multi<<<gP, 256, 0, stream>>>(xhw2b, W0fb, W0bb, b0f, b0b,
                                     nullptr, nullptr, Pbuf, 1,
                                     S_LEN, 1024, DIM);

  // 4) layer-0 bidirectional chunked scan -> X1b [S,512] bf16
  dim3 gS(NCHUNK, 2);
  lstm_scan<<<gS, 256, 0, stream>>>(Wq4, Wsc, h0q4b, h0sb, c0, 0, Pbuf, X1b);

  // 5) layer-1 input projections
  gemm_multi<<<gP, 256, 0, stream>>>(X1b, W1fb, W1bb, b1f, b1b,
                                     nullptr, nullptr, Pbuf, 1,
                                     S_LEN, 1024, 512);

  // 6) layer-1 chunked scan -> X1b reused as lstm_out (bf16)
  lstm_scan<<<gS, 256, 0, stream>>>(Wq4 + (size_t)2 * 1024 * 32, Wsc + 2048,
                                    h0q4b, h0sb, c0, 2, Pbuf, X1b);

  // 7) tag projection -> feats [S,12]
  dim3 gT(S_LEN / 128, 1, 1);
  gemm_multi<<<gT, 256, 0, stream>>>(X1b, Wtagb, nullptr, btag, nullptr,
                                     feats, nullptr, nullptr, 0,
                                     S_LEN, NTAG, 512);

  // 8) CRF log-partition
  crf_chunk<<<128, 192, 0, stream>>>(feats, trans, Mc);
  crf_fold<<<1, 64, 0, stream>>>(Mc, trans, (float*)d_out);
}